// Round 8
// baseline (263.795 us; speedup 1.0000x reference)
//
#include <hip/hip_runtime.h>
#include <hip/hip_bf16.h>

#define BB   8
#define LL   1024
#define DD   64
#define D2   128
#define D4   256
#define HH   8
#define DH   16

typedef __attribute__((ext_vector_type(8))) short short8;
typedef __attribute__((ext_vector_type(4))) float floatx4;

#define LOG2E 1.4426950408889634f
#define QK_SEED -66.54214054f

// attn split-K=4: 4 partials of 8192x128 floats, 4 lsum quarters
#define OB_QUAR 1048576
#define L_QUAR  65536

#define OFF_WIN1   0
#define OFF_WIN2   65536
#define OFF_LAY0   98304
#define LAY_STRIDE 131072
#define OFF_WQ     0
#define OFF_WK     16384
#define OFF_WV     32768
#define OFF_WO     49152
#define OFF_W1     65536
#define OFF_W2     98304
#define OFF_WH1    360448
#define OFF_WH2    393216

__device__ __forceinline__ float gelu_tanh(float u) {
  float y = 0.7978845608028654f * (u + 0.044715f * u * u * u);
  return __fdividef(u, 1.0f + __expf(-2.0f * y));
}

__device__ __forceinline__ float wave_reduce_sum(float v) {
#pragma unroll
  for (int m = 32; m >= 1; m >>= 1) v += __shfl_xor(v, m, 64);
  return v;
}

__device__ __forceinline__ unsigned short f2bf(float x) {
  unsigned u = __float_as_uint(x);
  u += 0x7fffu + ((u >> 16) & 1u);
  return (unsigned short)(u >> 16);
}

__device__ __forceinline__ float bf2f(unsigned short x) {
  return __uint_as_float(((unsigned)x) << 16);
}

__device__ __forceinline__ void split_bf(float v, unsigned short& hi,
                                         unsigned short& lo) {
  hi = f2bf(v);
  lo = f2bf(v - bf2f(hi));
}

__device__ __forceinline__ unsigned pack_bf2(float a, float b) {
  unsigned ua = __float_as_uint(a) + 0x8000u;
  unsigned ub = __float_as_uint(b) + 0x8000u;
  return __builtin_amdgcn_perm(ub, ua, 0x07060302u);
}

template <int K, int KP>
__device__ __forceinline__ floatx4 mfma_tile(
    const unsigned short* Ah, const unsigned short* Al,
    const unsigned short* __restrict__ Bh, const unsigned short* __restrict__ Bl,
    int lq, int quad, floatx4 C) {
  floatx4 C1 = {0.0f, 0.0f, 0.0f, 0.0f};
  floatx4 C2 = {0.0f, 0.0f, 0.0f, 0.0f};
#pragma unroll
  for (int kk = 0; kk < K; kk += 32) {
    short8 ah = *(const short8*)(Ah + lq * KP + kk + quad * 8);
    short8 al = *(const short8*)(Al + lq * KP + kk + quad * 8);
    short8 bh = *(const short8*)(Bh + lq * K + kk + quad * 8);
    short8 bl = *(const short8*)(Bl + lq * K + kk + quad * 8);
    C  = __builtin_amdgcn_mfma_f32_16x16x32_bf16(ah, bh, C, 0, 0, 0);
    C1 = __builtin_amdgcn_mfma_f32_16x16x32_bf16(al, bh, C1, 0, 0, 0);
    C2 = __builtin_amdgcn_mfma_f32_16x16x32_bf16(ah, bl, C2, 0, 0, 0);
  }
#pragma unroll
  for (int r = 0; r < 4; ++r) C[r] += C1[r] + C2[r];
  return C;
}

struct PrepArgs {
  const float* src[16];
  int Kd[16], Nd[16], dst[16], elems[16];
};

__global__ __launch_bounds__(256) void k_prep_bias(
    PrepArgs a, unsigned short* __restrict__ arena,
    const float* __restrict__ s, const float* __restrict__ rbf_c,
    const float* __restrict__ rbf_logw, const float* __restrict__ rbf_w,
    const float* __restrict__ rbf_b, unsigned short* __restrict__ biasT) {
  int bid = blockIdx.x, t = threadIdx.x;
  if (bid < 2048) {
    int mid = bid >> 7;
    int e = (bid & 127) * 256 + t;
    int KN = a.elems[mid];
    if (e >= KN) return;
    int K = a.Kd[mid], N = a.Nd[mid];
    int n = e / K, k = e - n * K;
    float wv = a.src[mid][k * N + n];
    unsigned short hi, lo;
    split_bf(wv, hi, lo);
    arena[a.dst[mid] + e] = hi;
    arena[a.dst[mid] + KN + e] = lo;
    return;
  }
  __shared__ float cs[16], iw[16];
  int rem = bid - 2048;
  int lay = rem >> 12;
  if (t < 16) {
    cs[t] = rbf_c[lay * 16 + t];
    iw[t] = 0.5f * __expf(-2.0f * rbf_logw[lay * 16 + t]);
  }
  __syncthreads();
  int id = (rem & 4095) * 256 + t;
  int q = id >> 10, k = id & 1023;
  float dd = s[q] - s[k];
  float acc[8];
#pragma unroll
  for (int h = 0; h < 8; ++h) acc[h] = rbf_b[lay * 8 + h];
#pragma unroll 1
  for (int f = 0; f < 16; ++f) {
    float e = dd - cs[f];
    float ph = __expf(-e * e * iw[f]);
#pragma unroll
    for (int h = 0; h < 8; ++h)
      acc[h] = fmaf(ph, rbf_w[lay * 128 + f * 8 + h], acc[h]);
  }
  unsigned short* bT = biasT + (size_t)lay * 8 * 1024 * 1024;
#pragma unroll
  for (int h = 0; h < 8; ++h)
    bT[(size_t)(h * 1024 + q) * 1024 + k] = f2bf(acc[h] * LOG2E);
}

__device__ __forceinline__ void qkv_tail(
    const float* xl, unsigned short* Sh, unsigned short* Sl,
    const unsigned short* __restrict__ arena, int lay,
    const float* __restrict__ ln_s, const float* __restrict__ ln_b,
    const float* __restrict__ bq, const float* __restrict__ bk,
    const float* __restrict__ bv, unsigned short* __restrict__ qo,
    unsigned short* __restrict__ ko, unsigned short* __restrict__ voT,
    int tok0, int t) {
  int w = t >> 6, lane = t & 63;
  int lq = lane & 15, quad = lane >> 4;
  float ss = ln_s[lay * 64 + lane], sb = ln_b[lay * 64 + lane];
#pragma unroll
  for (int tk = 0; tk < 4; ++tk) {
    int tok = w * 4 + tk;
    float v = xl[tok * 64 + lane];
    float s1 = v, s2 = v * v;
#pragma unroll
    for (int m = 32; m >= 1; m >>= 1) {
      s1 += __shfl_xor(s1, m, 64);
      s2 += __shfl_xor(s2, m, 64);
    }
    float mean = s1 * 0.015625f;
    float var = fmaf(-mean, mean, s2 * 0.015625f);
    float hv = (v - mean) * rsqrtf(var + 1e-6f) * ss + sb;
    unsigned short hi, lo;
    split_bf(hv, hi, lo);
    Sh[tok * 72 + lane] = hi;
    Sl[tok * 72 + lane] = lo;
  }
  __syncthreads();
  int b = tok0 >> 10, l0 = tok0 & 1023;
#pragma unroll 1
  for (int mat = 0; mat < 3; ++mat) {
    const unsigned short* Bh =
        arena + OFF_LAY0 + lay * LAY_STRIDE + mat * 16384;
    const unsigned short* Bl = Bh + 8192;
    const float* bias = (mat == 0 ? bq : mat == 1 ? bk : bv) + lay * 128;
#pragma unroll
    for (int j = 0; j < 2; ++j) {
      int tl = w + j * 4;
      int n = tl * 16 + lq;
      float bb = bias[n];
      floatx4 C = {bb, bb, bb, bb};
      C = mfma_tile<64, 72>(Sh, Sl, Bh + tl * 16 * 64, Bl + tl * 16 * 64,
                            lq, quad, C);
      if (mat < 2) {
        unsigned short* outp = (mat == 0 ? qo : ko);
        size_t basea = ((size_t)(b * 8 + tl) * 1024 + l0 + quad * 4) * 16 + lq;
#pragma unroll
        for (int r = 0; r < 4; ++r)
          outp[basea + (size_t)r * 16] = f2bf(C[r]);
      } else {
        size_t basev = ((size_t)(b * 8 + tl) * 16 + lq) * 1024 + l0 + quad * 4;
#pragma unroll
        for (int r = 0; r < 4; ++r)
          voT[basev + r] = f2bf(C[r]);
      }
    }
  }
}

__global__ __launch_bounds__(256, 2) void k_in_qkv(
    const float* __restrict__ embed, const float* __restrict__ z,
    const float* __restrict__ cond, const unsigned short* __restrict__ arena,
    const float* __restrict__ bin1, const float* __restrict__ bin2,
    float* __restrict__ x, const float* __restrict__ ln1_s,
    const float* __restrict__ ln1_b, const float* __restrict__ bq,
    const float* __restrict__ bk, const float* __restrict__ bv,
    unsigned short* __restrict__ qo, unsigned short* __restrict__ ko,
    unsigned short* __restrict__ voT) {
  __shared__ __align__(16) unsigned short Ah[16 * 136], Al[16 * 136];
  __shared__ __align__(16) unsigned short Hh[16 * 264], Hl[16 * 264];
  __shared__ __align__(16) unsigned short Sh[16 * 72], Sl[16 * 72];
  __shared__ float xl[16 * 64];
  int t = threadIdx.x, w = t >> 6, lane = t & 63;
  int lq = lane & 15, quad = lane >> 4;
  int tok0 = blockIdx.x * 16;
  for (int idx = t; idx < 2048; idx += 256) {
    int tok = idx >> 7, dim = idx & 127;
    int bl = tok0 + tok, l = bl & (LL - 1);
    float v;
    if (dim < 123) v = embed[l * 123 + dim];
    else if (dim == 123) v = z[bl];
    else v = cond[dim - 124];
    unsigned short hi, lo;
    split_bf(v, hi, lo);
    Ah[tok * 136 + dim] = hi;
    Al[tok * 136 + dim] = lo;
  }
  __syncthreads();
  const unsigned short* B1h = arena + OFF_WIN1;
  const unsigned short* B1l = B1h + 32768;
#pragma unroll
  for (int j = 0; j < 4; ++j) {
    int tl = w * 4 + j, n = tl * 16 + lq;
    float bb = bin1[n];
    floatx4 C = {bb, bb, bb, bb};
    C = mfma_tile<128, 136>(Ah, Al, B1h + tl * 16 * 128, B1l + tl * 16 * 128,
                            lq, quad, C);
#pragma unroll
    for (int r = 0; r < 4; ++r) {
      float g = gelu_tanh(C[r]);
      unsigned short hi, lo;
      split_bf(g, hi, lo);
      Hh[(quad * 4 + r) * 264 + n] = hi;
      Hl[(quad * 4 + r) * 264 + n] = lo;
    }
  }
  __syncthreads();
  const unsigned short* B2h = arena + OFF_WIN2;
  const unsigned short* B2l = B2h + 16384;
  {
    int n = w * 16 + lq;
    float bb = bin2[n];
    floatx4 C = {bb, bb, bb, bb};
    C = mfma_tile<256, 264>(Hh, Hl, B2h + w * 16 * 256, B2l + w * 16 * 256,
                            lq, quad, C);
#pragma unroll
    for (int r = 0; r < 4; ++r) {
      int m = quad * 4 + r;
      x[(size_t)(tok0 + m) * 64 + n] = C[r];
      xl[m * 64 + n] = C[r];
    }
  }
  __syncthreads();
  qkv_tail(xl, Sh, Sl, arena, 0, ln1_s, ln1_b, bq, bk, bv,
           qo, ko, voT, tok0, t);
}

// ---------------------------------------------------------------------------
// MFMA flash attention, SPLIT-K over 4 QUARTERS (grid 4096; quarter=bid>>10).
// No-max exp2 softmax is LINEAR in keys -> quarters combine by fixed-order
// addition in the consumer (bit-deterministic). Each block: 4 chunks of 64
// keys (half the barriers/critical path of split-2).
// ---------------------------------------------------------------------------
__global__ __launch_bounds__(256) void k_attn(
    const unsigned short* __restrict__ qg, const unsigned short* __restrict__ kg,
    const unsigned short* __restrict__ vgT, const unsigned short* __restrict__ biasT,
    float* __restrict__ og, float* __restrict__ lsum) {
  __shared__ __align__(16) unsigned short Kl[64 * 32];
  __shared__ __align__(16) unsigned short VT[16 * 72];
  __shared__ __align__(16) unsigned short Pl[4][16 * 72];
  __shared__ __align__(16) unsigned short Bch[64 * 72];
  int t = threadIdx.x, w = t >> 6, lane = t & 63;
  int lq = lane & 15, quad = lane >> 4;
  int bid = blockIdx.x;
  int quarter = bid >> 10;
  int rem = bid & 1023;
  int b = rem >> 7, h = (rem >> 4) & 7, qblk = rem & 15;
  int q0w = qblk * 64 + w * 16;
  int kbase = quarter * 256;
  size_t bh = (size_t)(b * 8 + h) * 1024;
  size_t bh16 = (size_t)(b * 8 + h) * 16;

  ((uint4*)Kl)[t] = uint4{0, 0, 0, 0};

  short8 Qb = {};
  if (quad < 2)
    Qb = *(const short8*)(qg + (bh + q0w + lq) * 16 + quad * 8);

  float l = 0.0f;
  floatx4 O = {0.0f, 0.0f, 0.0f, 0.0f};

  int key = t >> 2, dp = (t & 3) * 4;
  int drow = t >> 4, vcol = (t & 15) * 4;
  int qrow = t >> 2, bcol = (t & 3) * 16;
  const unsigned short* kgp = kg + (bh + kbase + key) * 16 + dp;
  const unsigned short* vgp = vgT + (bh16 + drow) * 1024 + kbase + vcol;
  const unsigned short* bgp =
      biasT + ((size_t)(h * 1024 + qblk * 64 + qrow)) * 1024 + kbase + bcol;

  uint2 kpre = *(const uint2*)(kgp);
  uint2 vpre = *(const uint2*)(vgp);
  uint4 bpre0 = *(const uint4*)(bgp);
  uint4 bpre1 = *(const uint4*)(bgp + 8);

#pragma unroll 1
  for (int kc = 0; kc < 256; kc += 64) {
    __syncthreads();
    *(uint2*)(Kl + key * 32 + dp) = kpre;
    *(uint2*)(VT + drow * 72 + vcol) = vpre;
    *(uint4*)(Bch + qrow * 72 + bcol) = bpre0;
    *(uint4*)(Bch + qrow * 72 + bcol + 8) = bpre1;
    __syncthreads();
    if (kc + 64 < 256) {
      kpre = *(const uint2*)(kgp + (size_t)(kc + 64) * 16);
      vpre = *(const uint2*)(vgp + (kc + 64));
      bpre0 = *(const uint4*)(bgp + (kc + 64));
      bpre1 = *(const uint4*)(bgp + (kc + 64) + 8);
    }
    float psum = 0.0f;
    unsigned short* pw = &Pl[w][lq * 72];
#pragma unroll
    for (int tile = 0; tile < 4; ++tile) {
      short8 A = *(const short8*)(Kl + (tile * 16 + lq) * 32 + quad * 8);
      floatx4 c = {QK_SEED, QK_SEED, QK_SEED, QK_SEED};
      c = __builtin_amdgcn_mfma_f32_16x16x32_bf16(A, Qb, c, 0, 0, 0);
      ushort4 bb = *(const ushort4*)(Bch + (w * 16 + lq) * 72 +
                                     tile * 16 + quad * 4);
      float p0 = exp2f(fmaf(c[0], 0.25f * LOG2E, bf2f(bb.x)));
      float p1 = exp2f(fmaf(c[1], 0.25f * LOG2E, bf2f(bb.y)));
      float p2 = exp2f(fmaf(c[2], 0.25f * LOG2E, bf2f(bb.z)));
      float p3 = exp2f(fmaf(c[3], 0.25f * LOG2E, bf2f(bb.w)));
      psum += (p0 + p1) + (p2 + p3);
      uint2 pk;
      pk.x = pack_bf2(p0, p1);
      pk.y = pack_bf2(p2, p3);
      *(uint2*)(pw + tile * 16 + quad * 4) = pk;
    }
    psum += __shfl_xor(psum, 16, 64);
    psum += __shfl_xor(psum, 32, 64);
    l += psum;
    asm volatile("s_waitcnt lgkmcnt(0)" ::: "memory");
#pragma unroll
    for (int i = 0; i < 2; ++i) {
      short8 Pa = *(const short8*)(pw + i * 32 + quad * 8);
      short8 Vb = *(const short8*)(&VT[lq * 72 + i * 32 + quad * 8]);
      O = __builtin_amdgcn_mfma_f32_16x16x32_bf16(Pa, Vb, O, 0, 0, 0);
    }
  }
  float* ogh = og + (size_t)quarter * OB_QUAR;
#pragma unroll
  for (int r = 0; r < 4; ++r)
    ogh[((size_t)(b * 1024 + q0w + quad * 4 + r)) * 128 + h * 16 + lq] = O[r];
  if (quad == 0)
    lsum[(size_t)quarter * L_QUAR + (size_t)(b * 1024 + q0w + lq) * 8 + h] = l;
}

__device__ __forceinline__ void pf_body(
    const float* __restrict__ ob, const float* __restrict__ lsum,
    const unsigned short* __restrict__ arena,
    const float* __restrict__ bo, float* __restrict__ x,
    const float* __restrict__ ln_s, const float* __restrict__ ln_b,
    const float* __restrict__ b1, const float* __restrict__ b2, int lay,
    unsigned short* Ah, unsigned short* Al, unsigned short* Sh,
    unsigned short* Sl, unsigned short* Hh, unsigned short* Hl, float* xl,
    int tok0, int t, bool write_x) {
  int w = t >> 6, lane = t & 63;
  int lq = lane & 15, quad = lane >> 4;
  const unsigned short* labase = arena + OFF_LAY0 + lay * LAY_STRIDE;
  const float* ob1 = ob + OB_QUAR;
  const float* ob2 = ob + 2 * OB_QUAR;
  const float* ob3 = ob + 3 * OB_QUAR;
  // stage attn-o: combine 4 quarters (fixed order), normalize, split
  for (int idx = t * 4; idx < 2048; idx += 1024) {
    int row = idx >> 7, col = idx & 127;
    int hh = col >> 4;
    int tok = tok0 + row;
    float lv = ((lsum[(size_t)tok * 8 + hh] +
                 lsum[L_QUAR + (size_t)tok * 8 + hh]) +
                (lsum[2 * L_QUAR + (size_t)tok * 8 + hh] +
                 lsum[3 * L_QUAR + (size_t)tok * 8 + hh]));
    float linv = 1.0f / lv;
    float4 v0 = *(const float4*)(ob + (size_t)tok * 128 + col);
    float4 v1 = *(const float4*)(ob1 + (size_t)tok * 128 + col);
    float4 v2 = *(const float4*)(ob2 + (size_t)tok * 128 + col);
    float4 v3 = *(const float4*)(ob3 + (size_t)tok * 128 + col);
    float4 v;
    v.x = ((v0.x + v1.x) + (v2.x + v3.x)) * linv;
    v.y = ((v0.y + v1.y) + (v2.y + v3.y)) * linv;
    v.z = ((v0.z + v1.z) + (v2.z + v3.z)) * linv;
    v.w = ((v0.w + v1.w) + (v2.w + v3.w)) * linv;
    unsigned short h0, e0, h1, e1, h2, e2, h3, e3;
    split_bf(v.x, h0, e0); split_bf(v.y, h1, e1);
    split_bf(v.z, h2, e2); split_bf(v.w, h3, e3);
    unsigned* ph = (unsigned*)(Ah + row * 136 + col);
    ph[0] = (unsigned)h0 | ((unsigned)h1 << 16);
    ph[1] = (unsigned)h2 | ((unsigned)h3 << 16);
    unsigned* pl = (unsigned*)(Al + row * 136 + col);
    pl[0] = (unsigned)e0 | ((unsigned)e1 << 16);
    pl[1] = (unsigned)e2 | ((unsigned)e3 << 16);
  }
  __syncthreads();
  {
    const unsigned short* Bh = labase + OFF_WO;
    const unsigned short* Bl = Bh + 8192;
    int n = w * 16 + lq;
    float bb = bo[lay * 64 + n];
    floatx4 C = {bb, bb, bb, bb};
    C = mfma_tile<128, 136>(Ah, Al, Bh + w * 16 * 128, Bl + w * 16 * 128,
                            lq, quad, C);
#pragma unroll
    for (int r = 0; r < 4; ++r) {
      int m = quad * 4 + r;
      xl[m * 64 + n] = x[(size_t)(tok0 + m) * 64 + n] + C[r];
    }
  }
  __syncthreads();
  {
    float ss = ln_s[lay * 64 + lane], sb = ln_b[lay * 64 + lane];
#pragma unroll
    for (int tk = 0; tk < 4; ++tk) {
      int tok = w * 4 + tk;
      float v = xl[tok * 64 + lane];
      float s1 = v, s2 = v * v;
#pragma unroll
      for (int m = 32; m >= 1; m >>= 1) {
        s1 += __shfl_xor(s1, m, 64);
        s2 += __shfl_xor(s2, m, 64);
      }
      float mean = s1 * 0.015625f;
      float var = fmaf(-mean, mean, s2 * 0.015625f);
      float hv = (v - mean) * rsqrtf(var + 1e-6f) * ss + sb;
      unsigned short hi, lo;
      split_bf(hv, hi, lo);
      Sh[tok * 72 + lane] = hi;
      Sl[tok * 72 + lane] = lo;
    }
  }
  __syncthreads();
  {
    const unsigned short* Bh = labase + OFF_W1;
    const unsigned short* Bl = Bh + 16384;
#pragma unroll
    for (int j = 0; j < 4; ++j) {
      int tl = w * 4 + j, n = tl * 16 + lq;
      float bb = b1[lay * 256 + n];
      floatx4 C = {bb, bb, bb, bb};
      C = mfma_tile<64, 72>(Sh, Sl, Bh + tl * 16 * 64, Bl + tl * 16 * 64,
                            lq, quad, C);
#pragma unroll
      for (int r = 0; r < 4; ++r) {
        float g = gelu_tanh(C[r]);
        unsigned short hi, lo;
        split_bf(g, hi, lo);
        Hh[(quad * 4 + r) * 264 + n] = hi;
        Hl[(quad * 4 + r) * 264 + n] = lo;
      }
    }
  }
  __syncthreads();
  {
    const unsigned short* Bh = labase + OFF_W2;
    const unsigned short* Bl = Bh + 16384;
    int n = w * 16 + lq;
    float bb = b2[lay * 64 + n];
    floatx4 C = {bb, bb, bb, bb};
    C = mfma_tile<256, 264>(Hh, Hl, Bh + w * 16 * 256, Bl + w * 16 * 256,
                            lq, quad, C);
#pragma unroll
    for (int r = 0; r < 4; ++r) {
      int m = quad * 4 + r;
      float xv = xl[m * 64 + n] + C[r];
      xl[m * 64 + n] = xv;
      if (write_x) x[(size_t)(tok0 + m) * 64 + n] = xv;
    }
  }
  __syncthreads();
}

__global__ __launch_bounds__(256, 2) void k_pf_qkv(
    const float* __restrict__ ob, const float* __restrict__ lsum,
    const unsigned short* __restrict__ arena,
    const float* __restrict__ bo, float* __restrict__ x,
    const float* __restrict__ ln2_s, const float* __restrict__ ln2_b,
    const float* __restrict__ b1, const float* __restrict__ b2, int lay,
    const float* __restrict__ ln1_s, const float* __restrict__ ln1_b,
    const float* __restrict__ bq, const float* __restrict__ bk,
    const float* __restrict__ bv, unsigned short* __restrict__ qo,
    unsigned short* __restrict__ ko, unsigned short* __restrict__ voT) {
  __shared__ __align__(16) unsigned short Ah[16 * 136], Al[16 * 136];
  __shared__ __align__(16) unsigned short Sh[16 * 72], Sl[16 * 72];
  __shared__ __align__(16) unsigned short Hh[16 * 264], Hl[16 * 264];
  __shared__ float xl[16 * 64];
  int t = threadIdx.x;
  int tok0 = blockIdx.x * 16;
  pf_body(ob, lsum, arena, bo, x, ln2_s, ln2_b, b1, b2, lay,
          Ah, Al, Sh, Sl, Hh, Hl, xl, tok0, t, true);
  qkv_tail(xl, Sh, Sl, arena, lay + 1, ln1_s, ln1_b, bq, bk, bv,
           qo, ko, voT, tok0, t);
}

__global__ __launch_bounds__(256, 2) void k_pf_head(
    const float* __restrict__ ob, const float* __restrict__ lsum,
    const unsigned short* __restrict__ arena,
    const float* __restrict__ bo, float* __restrict__ x,
    const float* __restrict__ ln2_s, const float* __restrict__ ln2_b,
    const float* __restrict__ b1, const float* __restrict__ b2, int lay,
    const float* __restrict__ bh1, const float* __restrict__ bh2,
    const float* __restrict__ Wh3, const float* __restrict__ bh3,
    float* __restrict__ out) {
  __shared__ __align__(16) unsigned short Ah[16 * 136], Al[16 * 136];
  __shared__ __align__(16) unsigned short Sh[16 * 72], Sl[16 * 72];
  __shared__ __align__(16) unsigned short Hh[16 * 264], Hl[16 * 264];
  __shared__ float xl[16 * 64];
  int t = threadIdx.x, w = t >> 6, lane = t & 63;
  int lq = lane & 15, quad = lane >> 4;
  int tok0 = blockIdx.x * 16;
  pf_body(ob, lsum, arena, bo, x, ln2_s, ln2_b, b1, b2, lay,
          Ah, Al, Sh, Sl, Hh, Hl, xl, tok0, t, false);
#pragma unroll
  for (int tk = 0; tk < 4; ++tk) {
    int tok = w * 4 + tk;
    unsigned short hi, lo;
    split_bf(xl[tok * 64 + lane], hi, lo);
    Sh[tok * 72 + lane] = hi;
    Sl[tok * 72 + lane] = lo;
  }
  __syncthreads();
  {
    const unsigned short* Bh = arena + OFF_WH1;
    const unsigned short* Bl = Bh + 16384;
#pragma unroll
    for (int j = 0; j < 4; ++j) {
      int tl = w * 4 + j, n = tl * 16 + lq;
      float bb = bh1[n];
      floatx4 C = {bb, bb, bb, bb};
      C = mfma_tile<64, 72>(Sh, Sl, Bh + tl * 16 * 64, Bl + tl * 16 * 64,
                            lq, quad, C);
#pragma unroll
      for (int r = 0; r < 4; ++r) {
        float g = gelu_tanh(C[r]);
        unsigned short hi, lo;
        split_bf(g, hi, lo);
        Hh[(quad * 4 + r) * 264 + n] = hi;
        Hl[(quad * 4 + r) * 264 + n] = lo;
      }
    }
  }
  __syncthreads();
  {
    const unsigned short* Bh = arena + OFF_WH2;
    const unsigned short* Bl = Bh + 16384;
    int n = w * 16 + lq;
    float bb = bh2[n];
    floatx4 C = {bb, bb, bb, bb};
    C = mfma_tile<256, 264>(Hh, Hl, Bh + w * 16 * 256, Bl + w * 16 * 256,
                            lq, quad, C);
    __syncthreads();
#pragma unroll
    for (int r = 0; r < 4; ++r)
      xl[(quad * 4 + r) * 64 + n] = gelu_tanh(C[r]);
  }
  __syncthreads();
  float wv3 = Wh3[lane];
#pragma unroll
  for (int tk = 0; tk < 4; ++tk) {
    int tok = w * 4 + tk;
    float v = xl[tok * 64 + lane] * wv3;
    float sum = wave_reduce_sum(v);
    if (lane == 0) out[tok0 + tok] = sum + bh3[0];
  }
}

extern "C" void kernel_launch(void* const* d_in, const int* in_sizes, int n_in,
                              void* d_out, int out_size, void* d_ws, size_t ws_size,
                              hipStream_t stream) {
  const float* z      = (const float*)d_in[0];
  const float* cond   = (const float*)d_in[1];
  const float* s      = (const float*)d_in[2];
  const float* embed  = (const float*)d_in[3];
  const float* Win1   = (const float*)d_in[4];
  const float* bin1   = (const float*)d_in[5];
  const float* Win2   = (const float*)d_in[6];
  const float* bin2   = (const float*)d_in[7];
  const float* ln1_s  = (const float*)d_in[8];
  const float* ln1_b  = (const float*)d_in[9];
  const float* ln2_s  = (const float*)d_in[10];
  const float* ln2_b  = (const float*)d_in[11];
  const float* Wq     = (const float*)d_in[12];
  const float* bq     = (const float*)d_in[13];
  const float* Wk     = (const float*)d_in[14];
  const float* bk     = (const float*)d_in[15];
  const float* Wv     = (const float*)d_in[16];
  const float* bv     = (const float*)d_in[17];
  const float* Wo     = (const float*)d_in[18];
  const float* bo     = (const float*)d_in[19];
  const float* rbf_c  = (const float*)d_in[20];
  const float* rbf_lw = (const float*)d_in[21];
  const float* rbf_w  = (const float*)d_in[22];
  const float* rbf_b  = (const float*)d_in[23];
  const float* W1     = (const float*)d_in[24];
  const float* b1     = (const float*)d_in[25];
  const float* W2     = (const float*)d_in[26];
  const float* b2     = (const float*)d_in[27];
  const float* Wh1    = (const float*)d_in[28];
  const float* bh1    = (const float*)d_in[29];
  const float* Wh2    = (const float*)d_in[30];
  const float* bh2    = (const float*)d_in[31];
  const float* Wh3    = (const float*)d_in[32];
  const float* bh3    = (const float*)d_in[33];

  char* base = (char*)d_ws;
  float*          x     = (float*)(base);                         // 2 MB
  unsigned short* qb    = (unsigned short*)(base + (2u << 20));   // 2 MB
  unsigned short* kb    = (unsigned short*)(base + (4u << 20));   // 2 MB
  unsigned short* vbT   = (unsigned short*)(base + (6u << 20));   // 2 MB
  float*          ob    = (float*)(base + (8u << 20));            // 4 x 4 MB
  float*          lsum  = (float*)(base + (24u << 20));           // 1 MB
  unsigned short* biasT = (unsigned short*)(base + (25u << 20));  // 2 x 16 MB
  unsigned short* arena = (unsigned short*)(base + (57u << 20));  // ~832 KB

  PrepArgs pa;
  auto set = [&](int i, const float* sp, int K, int N, int dst) {
    pa.src[i] = sp; pa.Kd[i] = K; pa.Nd[i] = N; pa.dst[i] = dst;
    pa.elems[i] = K * N;
  };
  set(0, Win1, 128, 256, OFF_WIN1);
  set(1, Win2, 256, 64, OFF_WIN2);
  for (int lay = 0; lay < 2; ++lay) {
    int lb = OFF_LAY0 + lay * LAY_STRIDE;
    set(2 + lay * 6, Wq + lay * 8192, 64, 128, lb + OFF_WQ);
    set(3 + lay * 6, Wk + lay * 8192, 64, 128, lb + OFF_WK);
    set(4 + lay * 6, Wv + lay * 8192, 64, 128, lb + OFF_WV);
    set(5 + lay * 6, Wo + lay * 8192, 128, 64, lb + OFF_WO);
    set(6 + lay * 6, W1 + lay * 16384, 64, 256, lb + OFF_W1);
    set(7 + lay * 6, W2 + lay * 16384, 256, 64, lb + OFF_W2);
  }
  set(14, Wh1, 64, 256, OFF_WH1);
  set(15, Wh2, 256, 64, OFF_WH2);

  k_prep_bias<<<2048 + 8192, 256, 0, stream>>>(pa, arena, s, rbf_c, rbf_lw,
                                               rbf_w, rbf_b, biasT);
  k_in_qkv<<<512, 256, 0, stream>>>(embed, z, cond, arena, bin1, bin2, x,
                                    ln1_s, ln1_b, bq, bk, bv, qb, kb, vbT);
  k_attn<<<4096, 256, 0, stream>>>(qb, kb, vbT, biasT, ob, lsum);
  k_pf_qkv<<<512, 256, 0, stream>>>(ob, lsum, arena, bo, x, ln2_s, ln2_b,
                                    b1, b2, 0, ln1_s, ln1_b, bq, bk, bv,
                                    qb, kb, vbT);
  k_attn<<<4096, 256, 0, stream>>>(qb, kb, vbT,
                                   biasT + (size_t)8 * 1024 * 1024, ob, lsum);
  k_pf_head<<<512, 256, 0, stream>>>(ob, lsum, arena, bo, x, ln2_s, ln2_b,
                                     b1, b2, 1, bh1, bh2, Wh3, bh3,
                                     (float*)d_out);
}

// Round 9
// 238.572 us; speedup vs baseline: 1.1057x; 1.1057x over previous
//
#include <hip/hip_runtime.h>
#include <hip/hip_bf16.h>

#define BB   8
#define LL   1024
#define DD   64
#define D2   128
#define D4   256
#define HH   8
#define DH   16

typedef __attribute__((ext_vector_type(8))) short short8;
typedef __attribute__((ext_vector_type(4))) float floatx4;

#define LOG2E 1.4426950408889634f
#define QK_SEED -66.54214054f

// attn split-K=4: 4 partials of 8192x128 floats, 4 lsum quarters
#define OB_QUAR 1048576
#define L_QUAR  65536

#define OFF_WIN1   0
#define OFF_WIN2   65536
#define OFF_LAY0   98304
#define LAY_STRIDE 131072
#define OFF_WQ     0
#define OFF_WK     16384
#define OFF_WV     32768
#define OFF_WO     49152
#define OFF_W1     65536
#define OFF_W2     98304
#define OFF_WH1    360448
#define OFF_WH2    393216

__device__ __forceinline__ float gelu_tanh(float u) {
  float y = 0.7978845608028654f * (u + 0.044715f * u * u * u);
  return __fdividef(u, 1.0f + __expf(-2.0f * y));
}

__device__ __forceinline__ float wave_reduce_sum(float v) {
#pragma unroll
  for (int m = 32; m >= 1; m >>= 1) v += __shfl_xor(v, m, 64);
  return v;
}

__device__ __forceinline__ unsigned short f2bf(float x) {
  unsigned u = __float_as_uint(x);
  u += 0x7fffu + ((u >> 16) & 1u);
  return (unsigned short)(u >> 16);
}

__device__ __forceinline__ float bf2f(unsigned short x) {
  return __uint_as_float(((unsigned)x) << 16);
}

__device__ __forceinline__ void split_bf(float v, unsigned short& hi,
                                         unsigned short& lo) {
  hi = f2bf(v);
  lo = f2bf(v - bf2f(hi));
}

__device__ __forceinline__ unsigned pack_bf2(float a, float b) {
  unsigned ua = __float_as_uint(a) + 0x8000u;
  unsigned ub = __float_as_uint(b) + 0x8000u;
  return __builtin_amdgcn_perm(ub, ua, 0x07060302u);
}

// MFMA-fragment arena layout: weight W_T[col][k] of a 16-col tile stored so
// that lane=(quad*16+lq) reads its 8 k-elems at tileBase+(kk/32)*512+lane*8
// -> ONE coalesced 1KB load per wave per kk-chunk (was 16-way scattered).
__device__ __forceinline__ int frag_off(int k, int n, int K) {
  return (n >> 4) * (K * 16) + ((k >> 5) << 9) + (((k >> 3) & 3) << 7) +
         ((n & 15) << 3) + (k & 7);
}

// 16x16 output tile over K, 3-term bf16 split, 3 independent accumulators.
// B is in fragment order (see frag_off); A from LDS (row stride KP shorts).
template <int K, int KP>
__device__ __forceinline__ floatx4 mfma_tile(
    const unsigned short* Ah, const unsigned short* Al,
    const unsigned short* __restrict__ Bf, const unsigned short* __restrict__ Bfl,
    int lane, int lq, int quad, floatx4 C) {
  floatx4 C1 = {0.0f, 0.0f, 0.0f, 0.0f};
  floatx4 C2 = {0.0f, 0.0f, 0.0f, 0.0f};
#pragma unroll
  for (int kk = 0; kk < K; kk += 32) {
    short8 ah = *(const short8*)(Ah + lq * KP + kk + quad * 8);
    short8 al = *(const short8*)(Al + lq * KP + kk + quad * 8);
    short8 bh = *(const short8*)(Bf + (kk >> 5) * 512 + lane * 8);
    short8 bl = *(const short8*)(Bfl + (kk >> 5) * 512 + lane * 8);
    C  = __builtin_amdgcn_mfma_f32_16x16x32_bf16(ah, bh, C, 0, 0, 0);
    C1 = __builtin_amdgcn_mfma_f32_16x16x32_bf16(al, bh, C1, 0, 0, 0);
    C2 = __builtin_amdgcn_mfma_f32_16x16x32_bf16(ah, bl, C2, 0, 0, 0);
  }
#pragma unroll
  for (int r = 0; r < 4; ++r) C[r] += C1[r] + C2[r];
  return C;
}

struct PrepArgs {
  const float* src[16];
  int Kd[16], Nd[16], dst[16], elems[16];
};

__global__ __launch_bounds__(256) void k_prep_bias(
    PrepArgs a, unsigned short* __restrict__ arena,
    const float* __restrict__ s, const float* __restrict__ rbf_c,
    const float* __restrict__ rbf_logw, const float* __restrict__ rbf_w,
    const float* __restrict__ rbf_b, unsigned short* __restrict__ biasT) {
  int bid = blockIdx.x, t = threadIdx.x;
  if (bid < 2048) {
    int mid = bid >> 7;
    int e = (bid & 127) * 256 + t;
    int KN = a.elems[mid];
    if (e >= KN) return;
    int K = a.Kd[mid], N = a.Nd[mid];
    int n = e / K, k = e - n * K;
    float wv = a.src[mid][k * N + n];
    unsigned short hi, lo;
    split_bf(wv, hi, lo);
    int fo = frag_off(k, n, K);
    arena[a.dst[mid] + fo] = hi;
    arena[a.dst[mid] + KN + fo] = lo;
    return;
  }
  __shared__ float cs[16], iw[16];
  int rem = bid - 2048;
  int lay = rem >> 12;
  if (t < 16) {
    cs[t] = rbf_c[lay * 16 + t];
    iw[t] = 0.5f * __expf(-2.0f * rbf_logw[lay * 16 + t]);
  }
  __syncthreads();
  int id = (rem & 4095) * 256 + t;
  int q = id >> 10, k = id & 1023;
  float dd = s[q] - s[k];
  float acc[8];
#pragma unroll
  for (int h = 0; h < 8; ++h) acc[h] = rbf_b[lay * 8 + h];
#pragma unroll 1
  for (int f = 0; f < 16; ++f) {
    float e = dd - cs[f];
    float ph = __expf(-e * e * iw[f]);
#pragma unroll
    for (int h = 0; h < 8; ++h)
      acc[h] = fmaf(ph, rbf_w[lay * 128 + f * 8 + h], acc[h]);
  }
  unsigned short* bT = biasT + (size_t)lay * 8 * 1024 * 1024;
#pragma unroll
  for (int h = 0; h < 8; ++h)
    bT[(size_t)(h * 1024 + q) * 1024 + k] = f2bf(acc[h] * LOG2E);
}

__device__ __forceinline__ void qkv_tail(
    const float* xl, unsigned short* Sh, unsigned short* Sl,
    const unsigned short* __restrict__ arena, int lay,
    const float* __restrict__ ln_s, const float* __restrict__ ln_b,
    const float* __restrict__ bq, const float* __restrict__ bk,
    const float* __restrict__ bv, unsigned short* __restrict__ qo,
    unsigned short* __restrict__ ko, unsigned short* __restrict__ voT,
    int tok0, int t) {
  int w = t >> 6, lane = t & 63;
  int lq = lane & 15, quad = lane >> 4;
  float ss = ln_s[lay * 64 + lane], sb = ln_b[lay * 64 + lane];
#pragma unroll
  for (int tk = 0; tk < 4; ++tk) {
    int tok = w * 4 + tk;
    float v = xl[tok * 64 + lane];
    float s1 = v, s2 = v * v;
#pragma unroll
    for (int m = 32; m >= 1; m >>= 1) {
      s1 += __shfl_xor(s1, m, 64);
      s2 += __shfl_xor(s2, m, 64);
    }
    float mean = s1 * 0.015625f;
    float var = fmaf(-mean, mean, s2 * 0.015625f);
    float hv = (v - mean) * rsqrtf(var + 1e-6f) * ss + sb;
    unsigned short hi, lo;
    split_bf(hv, hi, lo);
    Sh[tok * 72 + lane] = hi;
    Sl[tok * 72 + lane] = lo;
  }
  __syncthreads();
  int b = tok0 >> 10, l0 = tok0 & 1023;
#pragma unroll 1
  for (int mat = 0; mat < 3; ++mat) {
    const unsigned short* Bh =
        arena + OFF_LAY0 + lay * LAY_STRIDE + mat * 16384;
    const unsigned short* Bl = Bh + 8192;
    const float* bias = (mat == 0 ? bq : mat == 1 ? bk : bv) + lay * 128;
#pragma unroll
    for (int j = 0; j < 2; ++j) {
      int tl = w + j * 4;
      int n = tl * 16 + lq;
      float bb = bias[n];
      floatx4 C = {bb, bb, bb, bb};
      C = mfma_tile<64, 72>(Sh, Sl, Bh + tl * 16 * 64, Bl + tl * 16 * 64,
                            lane, lq, quad, C);
      if (mat < 2) {
        unsigned short* outp = (mat == 0 ? qo : ko);
        size_t basea = ((size_t)(b * 8 + tl) * 1024 + l0 + quad * 4) * 16 + lq;
#pragma unroll
        for (int r = 0; r < 4; ++r)
          outp[basea + (size_t)r * 16] = f2bf(C[r]);
      } else {
        size_t basev = ((size_t)(b * 8 + tl) * 16 + lq) * 1024 + l0 + quad * 4;
#pragma unroll
        for (int r = 0; r < 4; ++r)
          voT[basev + r] = f2bf(C[r]);
      }
    }
  }
}

__global__ __launch_bounds__(256, 2) void k_in_qkv(
    const float* __restrict__ embed, const float* __restrict__ z,
    const float* __restrict__ cond, const unsigned short* __restrict__ arena,
    const float* __restrict__ bin1, const float* __restrict__ bin2,
    float* __restrict__ x, const float* __restrict__ ln1_s,
    const float* __restrict__ ln1_b, const float* __restrict__ bq,
    const float* __restrict__ bk, const float* __restrict__ bv,
    unsigned short* __restrict__ qo, unsigned short* __restrict__ ko,
    unsigned short* __restrict__ voT) {
  __shared__ __align__(16) unsigned short Ah[16 * 136], Al[16 * 136];
  __shared__ __align__(16) unsigned short Hh[16 * 264], Hl[16 * 264];
  __shared__ __align__(16) unsigned short Sh[16 * 72], Sl[16 * 72];
  __shared__ float xl[16 * 64];
  int t = threadIdx.x, w = t >> 6, lane = t & 63;
  int lq = lane & 15, quad = lane >> 4;
  int tok0 = blockIdx.x * 16;
  for (int idx = t; idx < 2048; idx += 256) {
    int tok = idx >> 7, dim = idx & 127;
    int bl = tok0 + tok, l = bl & (LL - 1);
    float v;
    if (dim < 123) v = embed[l * 123 + dim];
    else if (dim == 123) v = z[bl];
    else v = cond[dim - 124];
    unsigned short hi, lo;
    split_bf(v, hi, lo);
    Ah[tok * 136 + dim] = hi;
    Al[tok * 136 + dim] = lo;
  }
  __syncthreads();
  const unsigned short* B1h = arena + OFF_WIN1;
  const unsigned short* B1l = B1h + 32768;
#pragma unroll
  for (int j = 0; j < 4; ++j) {
    int tl = w * 4 + j, n = tl * 16 + lq;
    float bb = bin1[n];
    floatx4 C = {bb, bb, bb, bb};
    C = mfma_tile<128, 136>(Ah, Al, B1h + tl * 16 * 128, B1l + tl * 16 * 128,
                            lane, lq, quad, C);
#pragma unroll
    for (int r = 0; r < 4; ++r) {
      float g = gelu_tanh(C[r]);
      unsigned short hi, lo;
      split_bf(g, hi, lo);
      Hh[(quad * 4 + r) * 264 + n] = hi;
      Hl[(quad * 4 + r) * 264 + n] = lo;
    }
  }
  __syncthreads();
  const unsigned short* B2h = arena + OFF_WIN2;
  const unsigned short* B2l = B2h + 16384;
  {
    int n = w * 16 + lq;
    float bb = bin2[n];
    floatx4 C = {bb, bb, bb, bb};
    C = mfma_tile<256, 264>(Hh, Hl, B2h + w * 16 * 256, B2l + w * 16 * 256,
                            lane, lq, quad, C);
#pragma unroll
    for (int r = 0; r < 4; ++r) {
      int m = quad * 4 + r;
      x[(size_t)(tok0 + m) * 64 + n] = C[r];
      xl[m * 64 + n] = C[r];
    }
  }
  __syncthreads();
  qkv_tail(xl, Sh, Sl, arena, 0, ln1_s, ln1_b, bq, bk, bv,
           qo, ko, voT, tok0, t);
}

// ---------------------------------------------------------------------------
// MFMA flash attention, SPLIT-K over 4 QUARTERS (grid 4096; quarter=bid>>10).
// Kl rows padded 32->40 shorts: old 64B rows put all 16 lq-lanes on 2 LDS
// banks (8-way conflict on the QK A-read); 80B rows spread to 8 banks.
// ---------------------------------------------------------------------------
__global__ __launch_bounds__(256) void k_attn(
    const unsigned short* __restrict__ qg, const unsigned short* __restrict__ kg,
    const unsigned short* __restrict__ vgT, const unsigned short* __restrict__ biasT,
    float* __restrict__ og, float* __restrict__ lsum) {
  __shared__ __align__(16) unsigned short Kl[64 * 40];
  __shared__ __align__(16) unsigned short VT[16 * 72];
  __shared__ __align__(16) unsigned short Pl[4][16 * 72];
  __shared__ __align__(16) unsigned short Bch[64 * 72];
  int t = threadIdx.x, w = t >> 6, lane = t & 63;
  int lq = lane & 15, quad = lane >> 4;
  int bid = blockIdx.x;
  int quarter = bid >> 10;
  int rem = bid & 1023;
  int b = rem >> 7, h = (rem >> 4) & 7, qblk = rem & 15;
  int q0w = qblk * 64 + w * 16;
  int kbase = quarter * 256;
  size_t bh = (size_t)(b * 8 + h) * 1024;
  size_t bh16 = (size_t)(b * 8 + h) * 16;

  ((uint4*)Kl)[t] = uint4{0, 0, 0, 0};  // zero rows + pad
  if (t < 64) ((uint4*)Kl)[256 + t] = uint4{0, 0, 0, 0};

  short8 Qb = {};
  if (quad < 2)
    Qb = *(const short8*)(qg + (bh + q0w + lq) * 16 + quad * 8);

  float l = 0.0f;
  floatx4 O = {0.0f, 0.0f, 0.0f, 0.0f};

  int key = t >> 2, dp = (t & 3) * 4;
  int drow = t >> 4, vcol = (t & 15) * 4;
  int qrow = t >> 2, bcol = (t & 3) * 16;
  const unsigned short* kgp = kg + (bh + kbase + key) * 16 + dp;
  const unsigned short* vgp = vgT + (bh16 + drow) * 1024 + kbase + vcol;
  const unsigned short* bgp =
      biasT + ((size_t)(h * 1024 + qblk * 64 + qrow)) * 1024 + kbase + bcol;

  uint2 kpre = *(const uint2*)(kgp);
  uint2 vpre = *(const uint2*)(vgp);
  uint4 bpre0 = *(const uint4*)(bgp);
  uint4 bpre1 = *(const uint4*)(bgp + 8);

#pragma unroll 1
  for (int kc = 0; kc < 256; kc += 64) {
    __syncthreads();
    *(uint2*)(Kl + key * 40 + dp) = kpre;
    *(uint2*)(VT + drow * 72 + vcol) = vpre;
    *(uint4*)(Bch + qrow * 72 + bcol) = bpre0;
    *(uint4*)(Bch + qrow * 72 + bcol + 8) = bpre1;
    __syncthreads();
    if (kc + 64 < 256) {
      kpre = *(const uint2*)(kgp + (size_t)(kc + 64) * 16);
      vpre = *(const uint2*)(vgp + (kc + 64));
      bpre0 = *(const uint4*)(bgp + (kc + 64));
      bpre1 = *(const uint4*)(bgp + (kc + 64) + 8);
    }
    float psum = 0.0f;
    unsigned short* pw = &Pl[w][lq * 72];
#pragma unroll
    for (int tile = 0; tile < 4; ++tile) {
      short8 A = *(const short8*)(Kl + (tile * 16 + lq) * 40 + quad * 8);
      floatx4 c = {QK_SEED, QK_SEED, QK_SEED, QK_SEED};
      c = __builtin_amdgcn_mfma_f32_16x16x32_bf16(A, Qb, c, 0, 0, 0);
      ushort4 bb = *(const ushort4*)(Bch + (w * 16 + lq) * 72 +
                                     tile * 16 + quad * 4);
      float p0 = exp2f(fmaf(c[0], 0.25f * LOG2E, bf2f(bb.x)));
      float p1 = exp2f(fmaf(c[1], 0.25f * LOG2E, bf2f(bb.y)));
      float p2 = exp2f(fmaf(c[2], 0.25f * LOG2E, bf2f(bb.z)));
      float p3 = exp2f(fmaf(c[3], 0.25f * LOG2E, bf2f(bb.w)));
      psum += (p0 + p1) + (p2 + p3);
      uint2 pk;
      pk.x = pack_bf2(p0, p1);
      pk.y = pack_bf2(p2, p3);
      *(uint2*)(pw + tile * 16 + quad * 4) = pk;
    }
    psum += __shfl_xor(psum, 16, 64);
    psum += __shfl_xor(psum, 32, 64);
    l += psum;
    asm volatile("s_waitcnt lgkmcnt(0)" ::: "memory");
#pragma unroll
    for (int i = 0; i < 2; ++i) {
      short8 Pa = *(const short8*)(pw + i * 32 + quad * 8);
      short8 Vb = *(const short8*)(&VT[lq * 72 + i * 32 + quad * 8]);
      O = __builtin_amdgcn_mfma_f32_16x16x32_bf16(Pa, Vb, O, 0, 0, 0);
    }
  }
  float* ogh = og + (size_t)quarter * OB_QUAR;
#pragma unroll
  for (int r = 0; r < 4; ++r)
    ogh[((size_t)(b * 1024 + q0w + quad * 4 + r)) * 128 + h * 16 + lq] = O[r];
  if (quad == 0)
    lsum[(size_t)quarter * L_QUAR + (size_t)(b * 1024 + q0w + lq) * 8 + h] = l;
}

__device__ __forceinline__ void pf_body(
    const float* __restrict__ ob, const float* __restrict__ lsum,
    const unsigned short* __restrict__ arena,
    const float* __restrict__ bo, float* __restrict__ x,
    const float* __restrict__ ln_s, const float* __restrict__ ln_b,
    const float* __restrict__ b1, const float* __restrict__ b2, int lay,
    unsigned short* Ah, unsigned short* Al, unsigned short* Sh,
    unsigned short* Sl, unsigned short* Hh, unsigned short* Hl, float* xl,
    int tok0, int t, bool write_x) {
  int w = t >> 6, lane = t & 63;
  int lq = lane & 15, quad = lane >> 4;
  const unsigned short* labase = arena + OFF_LAY0 + lay * LAY_STRIDE;
  const float* ob1 = ob + OB_QUAR;
  const float* ob2 = ob + 2 * OB_QUAR;
  const float* ob3 = ob + 3 * OB_QUAR;
  for (int idx = t * 4; idx < 2048; idx += 1024) {
    int row = idx >> 7, col = idx & 127;
    int hh = col >> 4;
    int tok = tok0 + row;
    float lv = ((lsum[(size_t)tok * 8 + hh] +
                 lsum[L_QUAR + (size_t)tok * 8 + hh]) +
                (lsum[2 * L_QUAR + (size_t)tok * 8 + hh] +
                 lsum[3 * L_QUAR + (size_t)tok * 8 + hh]));
    float linv = 1.0f / lv;
    float4 v0 = *(const float4*)(ob + (size_t)tok * 128 + col);
    float4 v1 = *(const float4*)(ob1 + (size_t)tok * 128 + col);
    float4 v2 = *(const float4*)(ob2 + (size_t)tok * 128 + col);
    float4 v3 = *(const float4*)(ob3 + (size_t)tok * 128 + col);
    float4 v;
    v.x = ((v0.x + v1.x) + (v2.x + v3.x)) * linv;
    v.y = ((v0.y + v1.y) + (v2.y + v3.y)) * linv;
    v.z = ((v0.z + v1.z) + (v2.z + v3.z)) * linv;
    v.w = ((v0.w + v1.w) + (v2.w + v3.w)) * linv;
    unsigned short h0, e0, h1, e1, h2, e2, h3, e3;
    split_bf(v.x, h0, e0); split_bf(v.y, h1, e1);
    split_bf(v.z, h2, e2); split_bf(v.w, h3, e3);
    unsigned* ph = (unsigned*)(Ah + row * 136 + col);
    ph[0] = (unsigned)h0 | ((unsigned)h1 << 16);
    ph[1] = (unsigned)h2 | ((unsigned)h3 << 16);
    unsigned* pl = (unsigned*)(Al + row * 136 + col);
    pl[0] = (unsigned)e0 | ((unsigned)e1 << 16);
    pl[1] = (unsigned)e2 | ((unsigned)e3 << 16);
  }
  __syncthreads();
  {
    const unsigned short* Bh = labase + OFF_WO;
    const unsigned short* Bl = Bh + 8192;
    int n = w * 16 + lq;
    float bb = bo[lay * 64 + n];
    floatx4 C = {bb, bb, bb, bb};
    C = mfma_tile<128, 136>(Ah, Al, Bh + w * 16 * 128, Bl + w * 16 * 128,
                            lane, lq, quad, C);
#pragma unroll
    for (int r = 0; r < 4; ++r) {
      int m = quad * 4 + r;
      xl[m * 64 + n] = x[(size_t)(tok0 + m) * 64 + n] + C[r];
    }
  }
  __syncthreads();
  {
    float ss = ln_s[lay * 64 + lane], sb = ln_b[lay * 64 + lane];
#pragma unroll
    for (int tk = 0; tk < 4; ++tk) {
      int tok = w * 4 + tk;
      float v = xl[tok * 64 + lane];
      float s1 = v, s2 = v * v;
#pragma unroll
      for (int m = 32; m >= 1; m >>= 1) {
        s1 += __shfl_xor(s1, m, 64);
        s2 += __shfl_xor(s2, m, 64);
      }
      float mean = s1 * 0.015625f;
      float var = fmaf(-mean, mean, s2 * 0.015625f);
      float hv = (v - mean) * rsqrtf(var + 1e-6f) * ss + sb;
      unsigned short hi, lo;
      split_bf(hv, hi, lo);
      Sh[tok * 72 + lane] = hi;
      Sl[tok * 72 + lane] = lo;
    }
  }
  __syncthreads();
  {
    const unsigned short* Bh = labase + OFF_W1;
    const unsigned short* Bl = Bh + 16384;
#pragma unroll
    for (int j = 0; j < 4; ++j) {
      int tl = w * 4 + j, n = tl * 16 + lq;
      float bb = b1[lay * 256 + n];
      floatx4 C = {bb, bb, bb, bb};
      C = mfma_tile<64, 72>(Sh, Sl, Bh + tl * 16 * 64, Bl + tl * 16 * 64,
                            lane, lq, quad, C);
#pragma unroll
      for (int r = 0; r < 4; ++r) {
        float g = gelu_tanh(C[r]);
        unsigned short hi, lo;
        split_bf(g, hi, lo);
        Hh[(quad * 4 + r) * 264 + n] = hi;
        Hl[(quad * 4 + r) * 264 + n] = lo;
      }
    }
  }
  __syncthreads();
  {
    const unsigned short* Bh = labase + OFF_W2;
    const unsigned short* Bl = Bh + 16384;
    int n = w * 16 + lq;
    float bb = b2[lay * 64 + n];
    floatx4 C = {bb, bb, bb, bb};
    C = mfma_tile<256, 264>(Hh, Hl, Bh + w * 16 * 256, Bl + w * 16 * 256,
                            lane, lq, quad, C);
#pragma unroll
    for (int r = 0; r < 4; ++r) {
      int m = quad * 4 + r;
      float xv = xl[m * 64 + n] + C[r];
      xl[m * 64 + n] = xv;
      if (write_x) x[(size_t)(tok0 + m) * 64 + n] = xv;
    }
  }
  __syncthreads();
}

__global__ __launch_bounds__(256, 2) void k_pf_qkv(
    const float* __restrict__ ob, const float* __restrict__ lsum,
    const unsigned short* __restrict__ arena,
    const float* __restrict__ bo, float* __restrict__ x,
    const float* __restrict__ ln2_s, const float* __restrict__ ln2_b,
    const float* __restrict__ b1, const float* __restrict__ b2, int lay,
    const float* __restrict__ ln1_s, const float* __restrict__ ln1_b,
    const float* __restrict__ bq, const float* __restrict__ bk,
    const float* __restrict__ bv, unsigned short* __restrict__ qo,
    unsigned short* __restrict__ ko, unsigned short* __restrict__ voT) {
  __shared__ __align__(16) unsigned short Ah[16 * 136], Al[16 * 136];
  __shared__ __align__(16) unsigned short Sh[16 * 72], Sl[16 * 72];
  __shared__ __align__(16) unsigned short Hh[16 * 264], Hl[16 * 264];
  __shared__ float xl[16 * 64];
  int t = threadIdx.x;
  int tok0 = blockIdx.x * 16;
  pf_body(ob, lsum, arena, bo, x, ln2_s, ln2_b, b1, b2, lay,
          Ah, Al, Sh, Sl, Hh, Hl, xl, tok0, t, true);
  qkv_tail(xl, Sh, Sl, arena, lay + 1, ln1_s, ln1_b, bq, bk, bv,
           qo, ko, voT, tok0, t);
}

__global__ __launch_bounds__(256, 2) void k_pf_head(
    const float* __restrict__ ob, const float* __restrict__ lsum,
    const unsigned short* __restrict__ arena,
    const float* __restrict__ bo, float* __restrict__ x,
    const float* __restrict__ ln2_s, const float* __restrict__ ln2_b,
    const float* __restrict__ b1, const float* __restrict__ b2, int lay,
    const float* __restrict__ bh1, const float* __restrict__ bh2,
    const float* __restrict__ Wh3, const float* __restrict__ bh3,
    float* __restrict__ out) {
  __shared__ __align__(16) unsigned short Ah[16 * 136], Al[16 * 136];
  __shared__ __align__(16) unsigned short Sh[16 * 72], Sl[16 * 72];
  __shared__ __align__(16) unsigned short Hh[16 * 264], Hl[16 * 264];
  __shared__ float xl[16 * 64];
  int t = threadIdx.x, w = t >> 6, lane = t & 63;
  int lq = lane & 15, quad = lane >> 4;
  int tok0 = blockIdx.x * 16;
  pf_body(ob, lsum, arena, bo, x, ln2_s, ln2_b, b1, b2, lay,
          Ah, Al, Sh, Sl, Hh, Hl, xl, tok0, t, false);
#pragma unroll
  for (int tk = 0; tk < 4; ++tk) {
    int tok = w * 4 + tk;
    unsigned short hi, lo;
    split_bf(xl[tok * 64 + lane], hi, lo);
    Sh[tok * 72 + lane] = hi;
    Sl[tok * 72 + lane] = lo;
  }
  __syncthreads();
  {
    const unsigned short* Bh = arena + OFF_WH1;
    const unsigned short* Bl = Bh + 16384;
#pragma unroll
    for (int j = 0; j < 4; ++j) {
      int tl = w * 4 + j, n = tl * 16 + lq;
      float bb = bh1[n];
      floatx4 C = {bb, bb, bb, bb};
      C = mfma_tile<64, 72>(Sh, Sl, Bh + tl * 16 * 64, Bl + tl * 16 * 64,
                            lane, lq, quad, C);
#pragma unroll
      for (int r = 0; r < 4; ++r) {
        float g = gelu_tanh(C[r]);
        unsigned short hi, lo;
        split_bf(g, hi, lo);
        Hh[(quad * 4 + r) * 264 + n] = hi;
        Hl[(quad * 4 + r) * 264 + n] = lo;
      }
    }
  }
  __syncthreads();
  {
    const unsigned short* Bh = arena + OFF_WH2;
    const unsigned short* Bl = Bh + 16384;
    int n = w * 16 + lq;
    float bb = bh2[n];
    floatx4 C = {bb, bb, bb, bb};
    C = mfma_tile<256, 264>(Hh, Hl, Bh + w * 16 * 256, Bl + w * 16 * 256,
                            lane, lq, quad, C);
    __syncthreads();
#pragma unroll
    for (int r = 0; r < 4; ++r)
      xl[(quad * 4 + r) * 64 + n] = gelu_tanh(C[r]);
  }
  __syncthreads();
  float wv3 = Wh3[lane];
#pragma unroll
  for (int tk = 0; tk < 4; ++tk) {
    int tok = w * 4 + tk;
    float v = xl[tok * 64 + lane] * wv3;
    float sum = wave_reduce_sum(v);
    if (lane == 0) out[tok0 + tok] = sum + bh3[0];
  }
}

extern "C" void kernel_launch(void* const* d_in, const int* in_sizes, int n_in,
                              void* d_out, int out_size, void* d_ws, size_t ws_size,
                              hipStream_t stream) {
  const float* z      = (const float*)d_in[0];
  const float* cond   = (const float*)d_in[1];
  const float* s      = (const float*)d_in[2];
  const float* embed  = (const float*)d_in[3];
  const float* Win1   = (const float*)d_in[4];
  const float* bin1   = (const float*)d_in[5];
  const float* Win2   = (const float*)d_in[6];
  const float* bin2   = (const float*)d_in[7];
  const float* ln1_s  = (const float*)d_in[8];
  const float* ln1_b  = (const float*)d_in[9];
  const float* ln2_s  = (const float*)d_in[10];
  const float* ln2_b  = (const float*)d_in[11];
  const float* Wq     = (const float*)d_in[12];
  const float* bq     = (const float*)d_in[13];
  const float* Wk     = (const float*)d_in[14];
  const float* bk     = (const float*)d_in[15];
  const float* Wv     = (const float*)d_in[16];
  const float* bv     = (const float*)d_in[17];
  const float* Wo     = (const float*)d_in[18];
  const float* bo     = (const float*)d_in[19];
  const float* rbf_c  = (const float*)d_in[20];
  const float* rbf_lw = (const float*)d_in[21];
  const float* rbf_w  = (const float*)d_in[22];
  const float* rbf_b  = (const float*)d_in[23];
  const float* W1     = (const float*)d_in[24];
  const float* b1     = (const float*)d_in[25];
  const float* W2     = (const float*)d_in[26];
  const float* b2     = (const float*)d_in[27];
  const float* Wh1    = (const float*)d_in[28];
  const float* bh1    = (const float*)d_in[29];
  const float* Wh2    = (const float*)d_in[30];
  const float* bh2    = (const float*)d_in[31];
  const float* Wh3    = (const float*)d_in[32];
  const float* bh3    = (const float*)d_in[33];

  char* base = (char*)d_ws;
  float*          x     = (float*)(base);                         // 2 MB
  unsigned short* qb    = (unsigned short*)(base + (2u << 20));   // 2 MB
  unsigned short* kb    = (unsigned short*)(base + (4u << 20));   // 2 MB
  unsigned short* vbT   = (unsigned short*)(base + (6u << 20));   // 2 MB
  float*          ob    = (float*)(base + (8u << 20));            // 4 x 4 MB
  float*          lsum  = (float*)(base + (24u << 20));           // 1 MB
  unsigned short* biasT = (unsigned short*)(base + (25u << 20));  // 2 x 16 MB
  unsigned short* arena = (unsigned short*)(base + (57u << 20));  // ~832 KB

  PrepArgs pa;
  auto set = [&](int i, const float* sp, int K, int N, int dst) {
    pa.src[i] = sp; pa.Kd[i] = K; pa.Nd[i] = N; pa.dst[i] = dst;
    pa.elems[i] = K * N;
  };
  set(0, Win1, 128, 256, OFF_WIN1);
  set(1, Win2, 256, 64, OFF_WIN2);
  for (int lay = 0; lay < 2; ++lay) {
    int lb = OFF_LAY0 + lay * LAY_STRIDE;
    set(2 + lay * 6, Wq + lay * 8192, 64, 128, lb + OFF_WQ);
    set(3 + lay * 6, Wk + lay * 8192, 64, 128, lb + OFF_WK);
    set(4 + lay * 6, Wv + lay * 8192, 64, 128, lb + OFF_WV);
    set(5 + lay * 6, Wo + lay * 8192, 128, 64, lb + OFF_WO);
    set(6 + lay * 6, W1 + lay * 16384, 64, 256, lb + OFF_W1);
    set(7 + lay * 6, W2 + lay * 16384, 256, 64, lb + OFF_W2);
  }
  set(14, Wh1, 64, 256, OFF_WH1);
  set(15, Wh2, 256, 64, OFF_WH2);

  k_prep_bias<<<2048 + 8192, 256, 0, stream>>>(pa, arena, s, rbf_c, rbf_lw,
                                               rbf_w, rbf_b, biasT);
  k_in_qkv<<<512, 256, 0, stream>>>(embed, z, cond, arena, bin1, bin2, x,
                                    ln1_s, ln1_b, bq, bk, bv, qb, kb, vbT);
  k_attn<<<4096, 256, 0, stream>>>(qb, kb, vbT, biasT, ob, lsum);
  k_pf_qkv<<<512, 256, 0, stream>>>(ob, lsum, arena, bo, x, ln2_s, ln2_b,
                                    b1, b2, 0, ln1_s, ln1_b, bq, bk, bv,
                                    qb, kb, vbT);
  k_attn<<<4096, 256, 0, stream>>>(qb, kb, vbT,
                                   biasT + (size_t)8 * 1024 * 1024, ob, lsum);
  k_pf_head<<<512, 256, 0, stream>>>(ob, lsum, arena, bo, x, ln2_s, ln2_b,
                                     b1, b2, 1, bh1, bh2, Wh3, bh3,
                                     (float*)d_out);
}

// Round 10
// 238.308 us; speedup vs baseline: 1.1069x; 1.0011x over previous
//
#include <hip/hip_runtime.h>
#include <hip/hip_bf16.h>

#define BB   8
#define LL   1024
#define DD   64
#define D2   128
#define D4   256
#define HH   8
#define DH   16

typedef __attribute__((ext_vector_type(8))) short short8;
typedef __attribute__((ext_vector_type(4))) float floatx4;

#define LOG2E 1.4426950408889634f
#define QK_SEED -66.54214054f

// attn split-K=4: 4 partials of 8192x128 floats, 4 lsum quarters
#define OB_QUAR 1048576
#define L_QUAR  65536

#define OFF_WIN1   0
#define OFF_WIN2   65536
#define OFF_LAY0   98304
#define LAY_STRIDE 131072
#define OFF_WQ     0
#define OFF_WK     16384
#define OFF_WV     32768
#define OFF_WO     49152
#define OFF_W1     65536
#define OFF_W2     98304
#define OFF_WH1    360448
#define OFF_WH2    393216

__device__ __forceinline__ float gelu_tanh(float u) {
  float y = 0.7978845608028654f * (u + 0.044715f * u * u * u);
  return __fdividef(u, 1.0f + __expf(-2.0f * y));
}

__device__ __forceinline__ float wave_reduce_sum(float v) {
#pragma unroll
  for (int m = 32; m >= 1; m >>= 1) v += __shfl_xor(v, m, 64);
  return v;
}

__device__ __forceinline__ unsigned short f2bf(float x) {
  unsigned u = __float_as_uint(x);
  u += 0x7fffu + ((u >> 16) & 1u);
  return (unsigned short)(u >> 16);
}

__device__ __forceinline__ float bf2f(unsigned short x) {
  return __uint_as_float(((unsigned)x) << 16);
}

__device__ __forceinline__ void split_bf(float v, unsigned short& hi,
                                         unsigned short& lo) {
  hi = f2bf(v);
  lo = f2bf(v - bf2f(hi));
}

__device__ __forceinline__ unsigned pack_bf2(float a, float b) {
  unsigned ua = __float_as_uint(a) + 0x8000u;
  unsigned ub = __float_as_uint(b) + 0x8000u;
  return __builtin_amdgcn_perm(ub, ua, 0x07060302u);
}

// MFMA-fragment arena layout (proven R9): lane reads its 8 k-elems at
// tileBase + (kk/32)*512 + lane*8 -> one coalesced 1KB wave-load.
__device__ __forceinline__ int frag_off(int k, int n, int K) {
  return (n >> 4) * (K * 16) + ((k >> 5) << 9) + (((k >> 3) & 3) << 7) +
         ((n & 15) << 3) + (k & 7);
}

// 16x16 output tile over K, 3-term bf16 split, 3 independent accumulators.
// B in fragment order; A from LDS row-major (stride KP shorts).
template <int K, int KP>
__device__ __forceinline__ floatx4 mfma_tile(
    const unsigned short* Ah, const unsigned short* Al,
    const unsigned short* __restrict__ Bf, const unsigned short* __restrict__ Bfl,
    int lane, int lq, int quad, floatx4 C) {
  floatx4 C1 = {0.0f, 0.0f, 0.0f, 0.0f};
  floatx4 C2 = {0.0f, 0.0f, 0.0f, 0.0f};
#pragma unroll
  for (int kk = 0; kk < K; kk += 32) {
    short8 ah = *(const short8*)(Ah + lq * KP + kk + quad * 8);
    short8 al = *(const short8*)(Al + lq * KP + kk + quad * 8);
    short8 bh = *(const short8*)(Bf + (kk >> 5) * 512 + lane * 8);
    short8 bl = *(const short8*)(Bfl + (kk >> 5) * 512 + lane * 8);
    C  = __builtin_amdgcn_mfma_f32_16x16x32_bf16(ah, bh, C, 0, 0, 0);
    C1 = __builtin_amdgcn_mfma_f32_16x16x32_bf16(al, bh, C1, 0, 0, 0);
    C2 = __builtin_amdgcn_mfma_f32_16x16x32_bf16(ah, bl, C2, 0, 0, 0);
  }
#pragma unroll
  for (int r = 0; r < 4; ++r) C[r] += C1[r] + C2[r];
  return C;
}

struct PrepArgs {
  const float* src[16];
  int Kd[16], Nd[16], dst[16], elems[16];
};

__global__ __launch_bounds__(256) void k_prep_bias(
    PrepArgs a, unsigned short* __restrict__ arena,
    const float* __restrict__ s, const float* __restrict__ rbf_c,
    const float* __restrict__ rbf_logw, const float* __restrict__ rbf_w,
    const float* __restrict__ rbf_b, unsigned short* __restrict__ biasT) {
  int bid = blockIdx.x, t = threadIdx.x;
  if (bid < 2048) {
    int mid = bid >> 7;
    int e = (bid & 127) * 256 + t;
    int KN = a.elems[mid];
    if (e >= KN) return;
    int K = a.Kd[mid], N = a.Nd[mid];
    int n = e / K, k = e - n * K;
    float wv = a.src[mid][k * N + n];
    unsigned short hi, lo;
    split_bf(wv, hi, lo);
    int fo = frag_off(k, n, K);
    arena[a.dst[mid] + fo] = hi;
    arena[a.dst[mid] + KN + fo] = lo;
    return;
  }
  __shared__ float cs[16], iw[16];
  int rem = bid - 2048;
  int lay = rem >> 12;
  if (t < 16) {
    cs[t] = rbf_c[lay * 16 + t];
    iw[t] = 0.5f * __expf(-2.0f * rbf_logw[lay * 16 + t]);
  }
  __syncthreads();
  int id = (rem & 4095) * 256 + t;
  int q = id >> 10, k = id & 1023;
  float dd = s[q] - s[k];
  float acc[8];
#pragma unroll
  for (int h = 0; h < 8; ++h) acc[h] = rbf_b[lay * 8 + h];
#pragma unroll 1
  for (int f = 0; f < 16; ++f) {
    float e = dd - cs[f];
    float ph = __expf(-e * e * iw[f]);
#pragma unroll
    for (int h = 0; h < 8; ++h)
      acc[h] = fmaf(ph, rbf_w[lay * 128 + f * 8 + h], acc[h]);
  }
  unsigned short* bT = biasT + (size_t)lay * 8 * 1024 * 1024;
#pragma unroll
  for (int h = 0; h < 8; ++h)
    bT[(size_t)(h * 1024 + q) * 1024 + k] = f2bf(acc[h] * LOG2E);
}

// QKV tail (8-wave version): LN over 16 tokens (2/wave); each wave owns one
// head tile (tl = w) for all 3 mats, K=64 unsplit.
__device__ __forceinline__ void qkv_tail(
    const float* xl, unsigned short* Sh, unsigned short* Sl,
    const unsigned short* __restrict__ arena, int lay,
    const float* __restrict__ ln_s, const float* __restrict__ ln_b,
    const float* __restrict__ bq, const float* __restrict__ bk,
    const float* __restrict__ bv, unsigned short* __restrict__ qo,
    unsigned short* __restrict__ ko, unsigned short* __restrict__ voT,
    int tok0, int t) {
  int w = t >> 6, lane = t & 63;
  int lq = lane & 15, quad = lane >> 4;
  float ss = ln_s[lay * 64 + lane], sb = ln_b[lay * 64 + lane];
#pragma unroll
  for (int tk = 0; tk < 2; ++tk) {
    int tok = w * 2 + tk;
    float v = xl[tok * 64 + lane];
    float s1 = v, s2 = v * v;
#pragma unroll
    for (int m = 32; m >= 1; m >>= 1) {
      s1 += __shfl_xor(s1, m, 64);
      s2 += __shfl_xor(s2, m, 64);
    }
    float mean = s1 * 0.015625f;
    float var = fmaf(-mean, mean, s2 * 0.015625f);
    float hv = (v - mean) * rsqrtf(var + 1e-6f) * ss + sb;
    unsigned short hi, lo;
    split_bf(hv, hi, lo);
    Sh[tok * 72 + lane] = hi;
    Sl[tok * 72 + lane] = lo;
  }
  __syncthreads();
  int b = tok0 >> 10, l0 = tok0 & 1023;
  int tl = w;  // head tile owned by this wave
#pragma unroll 1
  for (int mat = 0; mat < 3; ++mat) {
    const unsigned short* Bh =
        arena + OFF_LAY0 + lay * LAY_STRIDE + mat * 16384;
    const unsigned short* Bl = Bh + 8192;
    const float* bias = (mat == 0 ? bq : mat == 1 ? bk : bv) + lay * 128;
    int n = tl * 16 + lq;
    float bb = bias[n];
    floatx4 C = {bb, bb, bb, bb};
    C = mfma_tile<64, 72>(Sh, Sl, Bh + tl * 16 * 64, Bl + tl * 16 * 64,
                          lane, lq, quad, C);
    if (mat < 2) {
      unsigned short* outp = (mat == 0 ? qo : ko);
      size_t basea = ((size_t)(b * 8 + tl) * 1024 + l0 + quad * 4) * 16 + lq;
#pragma unroll
      for (int r = 0; r < 4; ++r)
        outp[basea + (size_t)r * 16] = f2bf(C[r]);
    } else {
      size_t basev = ((size_t)(b * 8 + tl) * 16 + lq) * 1024 + l0 + quad * 4;
#pragma unroll
      for (int r = 0; r < 4; ++r)
        voT[basev + r] = f2bf(C[r]);
    }
  }
}

// ---------------------------------------------------------------------------
// K1: input MLP + LN1 + QKV (layer 0). 16 tokens/block, 512 THREADS (8 waves)
// -> 16 waves/CU at constant total work. G1 split by cols (2 tiles/wave);
// G2 (K=256) split across wave pairs with LDS reduce.
// ---------------------------------------------------------------------------
__global__ __launch_bounds__(512, 4) void k_in_qkv(
    const float* __restrict__ embed, const float* __restrict__ z,
    const float* __restrict__ cond, const unsigned short* __restrict__ arena,
    const float* __restrict__ bin1, const float* __restrict__ bin2,
    float* __restrict__ x, const float* __restrict__ ln1_s,
    const float* __restrict__ ln1_b, const float* __restrict__ bq,
    const float* __restrict__ bk, const float* __restrict__ bv,
    unsigned short* __restrict__ qo, unsigned short* __restrict__ ko,
    unsigned short* __restrict__ voT) {
  __shared__ __align__(16) unsigned short Ah[16 * 136], Al[16 * 136];
  __shared__ __align__(16) unsigned short Hh[16 * 264], Hl[16 * 264];
  __shared__ __align__(16) unsigned short Sh[16 * 72], Sl[16 * 72];
  __shared__ float xl[16 * 64];
  __shared__ __align__(16) float red[4 * 64 * 4];
  int t = threadIdx.x, w = t >> 6, lane = t & 63;
  int lq = lane & 15, quad = lane >> 4;
  int tok0 = blockIdx.x * 16;
  for (int idx = t; idx < 2048; idx += 512) {
    int tok = idx >> 7, dim = idx & 127;
    int bl = tok0 + tok, l = bl & (LL - 1);
    float v;
    if (dim < 123) v = embed[l * 123 + dim];
    else if (dim == 123) v = z[bl];
    else v = cond[dim - 124];
    unsigned short hi, lo;
    split_bf(v, hi, lo);
    Ah[tok * 136 + dim] = hi;
    Al[tok * 136 + dim] = lo;
  }
  __syncthreads();
  // G1: 128 -> 256, gelu. 16 col-tiles over 8 waves.
  const unsigned short* B1h = arena + OFF_WIN1;
  const unsigned short* B1l = B1h + 32768;
#pragma unroll
  for (int j = 0; j < 2; ++j) {
    int tl = w * 2 + j, n = tl * 16 + lq;
    float bb = bin1[n];
    floatx4 C = {bb, bb, bb, bb};
    C = mfma_tile<128, 136>(Ah, Al, B1h + tl * 16 * 128, B1l + tl * 16 * 128,
                            lane, lq, quad, C);
#pragma unroll
    for (int r = 0; r < 4; ++r) {
      float g = gelu_tanh(C[r]);
      unsigned short hi, lo;
      split_bf(g, hi, lo);
      Hh[(quad * 4 + r) * 264 + n] = hi;
      Hl[(quad * 4 + r) * 264 + n] = lo;
    }
  }
  __syncthreads();
  // G2: 256 -> 64. 4 col-tiles; wave pairs split K (0-127 / 128-255).
  {
    const unsigned short* B2h = arena + OFF_WIN2;
    const unsigned short* B2l = B2h + 16384;
    int tile = w & 3, kh = w >> 2, koff = kh * 128;
    int n = tile * 16 + lq;
    floatx4 C = {0.0f, 0.0f, 0.0f, 0.0f};
    if (kh == 0) {
      float bb = bin2[n];
      C[0] = bb; C[1] = bb; C[2] = bb; C[3] = bb;
    }
    C = mfma_tile<128, 264>(Hh + koff, Hl + koff,
                            B2h + tile * 16 * 256 + (koff >> 5) * 512,
                            B2l + tile * 16 * 256 + (koff >> 5) * 512,
                            lane, lq, quad, C);
    if (kh) *(floatx4*)&red[(tile * 64 + lane) * 4] = C;
    __syncthreads();
    if (!kh) {
      floatx4 Cp = *(const floatx4*)&red[(tile * 64 + lane) * 4];
#pragma unroll
      for (int r = 0; r < 4; ++r) {
        int m = quad * 4 + r;
        float cv = C[r] + Cp[r];
        x[(size_t)(tok0 + m) * 64 + n] = cv;
        xl[m * 64 + n] = cv;
      }
    }
  }
  __syncthreads();
  qkv_tail(xl, Sh, Sl, arena, 0, ln1_s, ln1_b, bq, bk, bv,
           qo, ko, voT, tok0, t);
}

// ---------------------------------------------------------------------------
// MFMA flash attention, SPLIT-K over 4 QUARTERS (grid 4096) — unchanged R9.
// ---------------------------------------------------------------------------
__global__ __launch_bounds__(256) void k_attn(
    const unsigned short* __restrict__ qg, const unsigned short* __restrict__ kg,
    const unsigned short* __restrict__ vgT, const unsigned short* __restrict__ biasT,
    float* __restrict__ og, float* __restrict__ lsum) {
  __shared__ __align__(16) unsigned short Kl[64 * 40];
  __shared__ __align__(16) unsigned short VT[16 * 72];
  __shared__ __align__(16) unsigned short Pl[4][16 * 72];
  __shared__ __align__(16) unsigned short Bch[64 * 72];
  int t = threadIdx.x, w = t >> 6, lane = t & 63;
  int lq = lane & 15, quad = lane >> 4;
  int bid = blockIdx.x;
  int quarter = bid >> 10;
  int rem = bid & 1023;
  int b = rem >> 7, h = (rem >> 4) & 7, qblk = rem & 15;
  int q0w = qblk * 64 + w * 16;
  int kbase = quarter * 256;
  size_t bh = (size_t)(b * 8 + h) * 1024;
  size_t bh16 = (size_t)(b * 8 + h) * 16;

  ((uint4*)Kl)[t] = uint4{0, 0, 0, 0};
  if (t < 64) ((uint4*)Kl)[256 + t] = uint4{0, 0, 0, 0};

  short8 Qb = {};
  if (quad < 2)
    Qb = *(const short8*)(qg + (bh + q0w + lq) * 16 + quad * 8);

  float l = 0.0f;
  floatx4 O = {0.0f, 0.0f, 0.0f, 0.0f};

  int key = t >> 2, dp = (t & 3) * 4;
  int drow = t >> 4, vcol = (t & 15) * 4;
  int qrow = t >> 2, bcol = (t & 3) * 16;
  const unsigned short* kgp = kg + (bh + kbase + key) * 16 + dp;
  const unsigned short* vgp = vgT + (bh16 + drow) * 1024 + kbase + vcol;
  const unsigned short* bgp =
      biasT + ((size_t)(h * 1024 + qblk * 64 + qrow)) * 1024 + kbase + bcol;

  uint2 kpre = *(const uint2*)(kgp);
  uint2 vpre = *(const uint2*)(vgp);
  uint4 bpre0 = *(const uint4*)(bgp);
  uint4 bpre1 = *(const uint4*)(bgp + 8);

#pragma unroll 1
  for (int kc = 0; kc < 256; kc += 64) {
    __syncthreads();
    *(uint2*)(Kl + key * 40 + dp) = kpre;
    *(uint2*)(VT + drow * 72 + vcol) = vpre;
    *(uint4*)(Bch + qrow * 72 + bcol) = bpre0;
    *(uint4*)(Bch + qrow * 72 + bcol + 8) = bpre1;
    __syncthreads();
    if (kc + 64 < 256) {
      kpre = *(const uint2*)(kgp + (size_t)(kc + 64) * 16);
      vpre = *(const uint2*)(vgp + (kc + 64));
      bpre0 = *(const uint4*)(bgp + (kc + 64));
      bpre1 = *(const uint4*)(bgp + (kc + 64) + 8);
    }
    float psum = 0.0f;
    unsigned short* pw = &Pl[w][lq * 72];
#pragma unroll
    for (int tile = 0; tile < 4; ++tile) {
      short8 A = *(const short8*)(Kl + (tile * 16 + lq) * 40 + quad * 8);
      floatx4 c = {QK_SEED, QK_SEED, QK_SEED, QK_SEED};
      c = __builtin_amdgcn_mfma_f32_16x16x32_bf16(A, Qb, c, 0, 0, 0);
      ushort4 bb = *(const ushort4*)(Bch + (w * 16 + lq) * 72 +
                                     tile * 16 + quad * 4);
      float p0 = exp2f(fmaf(c[0], 0.25f * LOG2E, bf2f(bb.x)));
      float p1 = exp2f(fmaf(c[1], 0.25f * LOG2E, bf2f(bb.y)));
      float p2 = exp2f(fmaf(c[2], 0.25f * LOG2E, bf2f(bb.z)));
      float p3 = exp2f(fmaf(c[3], 0.25f * LOG2E, bf2f(bb.w)));
      psum += (p0 + p1) + (p2 + p3);
      uint2 pk;
      pk.x = pack_bf2(p0, p1);
      pk.y = pack_bf2(p2, p3);
      *(uint2*)(pw + tile * 16 + quad * 4) = pk;
    }
    psum += __shfl_xor(psum, 16, 64);
    psum += __shfl_xor(psum, 32, 64);
    l += psum;
    asm volatile("s_waitcnt lgkmcnt(0)" ::: "memory");
#pragma unroll
    for (int i = 0; i < 2; ++i) {
      short8 Pa = *(const short8*)(pw + i * 32 + quad * 8);
      short8 Vb = *(const short8*)(&VT[lq * 72 + i * 32 + quad * 8]);
      O = __builtin_amdgcn_mfma_f32_16x16x32_bf16(Pa, Vb, O, 0, 0, 0);
    }
  }
  float* ogh = og + (size_t)quarter * OB_QUAR;
#pragma unroll
  for (int r = 0; r < 4; ++r)
    ogh[((size_t)(b * 1024 + q0w + quad * 4 + r)) * 128 + h * 16 + lq] = O[r];
  if (quad == 0)
    lsum[(size_t)quarter * L_QUAR + (size_t)(b * 1024 + q0w + lq) * 8 + h] = l;
}

// proj+LN2+FFN body, 16 tokens, 8 waves. proj & FFN-G2 split K across wave
// pairs (fixed-order LDS reduce); FFN-G1 splits cols.
__device__ __forceinline__ void pf_body(
    const float* __restrict__ ob, const float* __restrict__ lsum,
    const unsigned short* __restrict__ arena,
    const float* __restrict__ bo, float* __restrict__ x,
    const float* __restrict__ ln_s, const float* __restrict__ ln_b,
    const float* __restrict__ b1, const float* __restrict__ b2, int lay,
    unsigned short* Ah, unsigned short* Al, unsigned short* Sh,
    unsigned short* Sl, unsigned short* Hh, unsigned short* Hl, float* xl,
    float* red, int tok0, int t, bool write_x) {
  int w = t >> 6, lane = t & 63;
  int lq = lane & 15, quad = lane >> 4;
  const unsigned short* labase = arena + OFF_LAY0 + lay * LAY_STRIDE;
  const float* ob1 = ob + OB_QUAR;
  const float* ob2 = ob + 2 * OB_QUAR;
  const float* ob3 = ob + 3 * OB_QUAR;
  // stage attn-o: combine 4 quarters, normalize, split. 512 thr x 4 elems.
  {
    int idx = t * 4;
    int row = idx >> 7, col = idx & 127;
    int hh = col >> 4;
    int tok = tok0 + row;
    float lv = ((lsum[(size_t)tok * 8 + hh] +
                 lsum[L_QUAR + (size_t)tok * 8 + hh]) +
                (lsum[2 * L_QUAR + (size_t)tok * 8 + hh] +
                 lsum[3 * L_QUAR + (size_t)tok * 8 + hh]));
    float linv = 1.0f / lv;
    float4 v0 = *(const float4*)(ob + (size_t)tok * 128 + col);
    float4 v1 = *(const float4*)(ob1 + (size_t)tok * 128 + col);
    float4 v2 = *(const float4*)(ob2 + (size_t)tok * 128 + col);
    float4 v3 = *(const float4*)(ob3 + (size_t)tok * 128 + col);
    float4 v;
    v.x = ((v0.x + v1.x) + (v2.x + v3.x)) * linv;
    v.y = ((v0.y + v1.y) + (v2.y + v3.y)) * linv;
    v.z = ((v0.z + v1.z) + (v2.z + v3.z)) * linv;
    v.w = ((v0.w + v1.w) + (v2.w + v3.w)) * linv;
    unsigned short h0, e0, h1, e1, h2, e2, h3, e3;
    split_bf(v.x, h0, e0); split_bf(v.y, h1, e1);
    split_bf(v.z, h2, e2); split_bf(v.w, h3, e3);
    unsigned* ph = (unsigned*)(Ah + row * 136 + col);
    ph[0] = (unsigned)h0 | ((unsigned)h1 << 16);
    ph[1] = (unsigned)h2 | ((unsigned)h3 << 16);
    unsigned* pl = (unsigned*)(Al + row * 136 + col);
    pl[0] = (unsigned)e0 | ((unsigned)e1 << 16);
    pl[1] = (unsigned)e2 | ((unsigned)e3 << 16);
  }
  __syncthreads();
  // proj: 128 -> 64, 4 col-tiles; wave pairs split K (0-63 / 64-127).
  {
    const unsigned short* Bh = labase + OFF_WO;
    const unsigned short* Bl = Bh + 8192;
    int tile = w & 3, kh = w >> 2, koff = kh * 64;
    int n = tile * 16 + lq;
    floatx4 C = {0.0f, 0.0f, 0.0f, 0.0f};
    if (kh == 0) {
      float bb = bo[lay * 64 + n];
      C[0] = bb; C[1] = bb; C[2] = bb; C[3] = bb;
    }
    C = mfma_tile<64, 136>(Ah + koff, Al + koff,
                           Bh + tile * 16 * 128 + (koff >> 5) * 512,
                           Bl + tile * 16 * 128 + (koff >> 5) * 512,
                           lane, lq, quad, C);
    if (kh) *(floatx4*)&red[(tile * 64 + lane) * 4] = C;
    __syncthreads();
    if (!kh) {
      floatx4 Cp = *(const floatx4*)&red[(tile * 64 + lane) * 4];
#pragma unroll
      for (int r = 0; r < 4; ++r) {
        int m = quad * 4 + r;
        xl[m * 64 + n] = x[(size_t)(tok0 + m) * 64 + n] + C[r] + Cp[r];
      }
    }
  }
  __syncthreads();
  // LN2 -> Sh/Sl (16 tokens over 8 waves)
  {
    float ss = ln_s[lay * 64 + lane], sb = ln_b[lay * 64 + lane];
#pragma unroll
    for (int tk = 0; tk < 2; ++tk) {
      int tok = w * 2 + tk;
      float v = xl[tok * 64 + lane];
      float s1 = v, s2 = v * v;
#pragma unroll
      for (int m = 32; m >= 1; m >>= 1) {
        s1 += __shfl_xor(s1, m, 64);
        s2 += __shfl_xor(s2, m, 64);
      }
      float mean = s1 * 0.015625f;
      float var = fmaf(-mean, mean, s2 * 0.015625f);
      float hv = (v - mean) * rsqrtf(var + 1e-6f) * ss + sb;
      unsigned short hi, lo;
      split_bf(hv, hi, lo);
      Sh[tok * 72 + lane] = hi;
      Sl[tok * 72 + lane] = lo;
    }
  }
  __syncthreads();
  // FFN G1: 64 -> 256, gelu. 16 col-tiles over 8 waves.
  {
    const unsigned short* Bh = labase + OFF_W1;
    const unsigned short* Bl = Bh + 16384;
#pragma unroll
    for (int j = 0; j < 2; ++j) {
      int tl = w * 2 + j, n = tl * 16 + lq;
      float bb = b1[lay * 256 + n];
      floatx4 C = {bb, bb, bb, bb};
      C = mfma_tile<64, 72>(Sh, Sl, Bh + tl * 16 * 64, Bl + tl * 16 * 64,
                            lane, lq, quad, C);
#pragma unroll
      for (int r = 0; r < 4; ++r) {
        float g = gelu_tanh(C[r]);
        unsigned short hi, lo;
        split_bf(g, hi, lo);
        Hh[(quad * 4 + r) * 264 + n] = hi;
        Hl[(quad * 4 + r) * 264 + n] = lo;
      }
    }
  }
  __syncthreads();
  // FFN G2: 256 -> 64, 4 col-tiles; wave pairs split K (0-127 / 128-255).
  {
    const unsigned short* Bh = labase + OFF_W2;
    const unsigned short* Bl = Bh + 16384;
    int tile = w & 3, kh = w >> 2, koff = kh * 128;
    int n = tile * 16 + lq;
    floatx4 C = {0.0f, 0.0f, 0.0f, 0.0f};
    if (kh == 0) {
      float bb = b2[lay * 64 + n];
      C[0] = bb; C[1] = bb; C[2] = bb; C[3] = bb;
    }
    C = mfma_tile<128, 264>(Hh + koff, Hl + koff,
                            Bh + tile * 16 * 256 + (koff >> 5) * 512,
                            Bl + tile * 16 * 256 + (koff >> 5) * 512,
                            lane, lq, quad, C);
    if (kh) *(floatx4*)&red[(tile * 64 + lane) * 4] = C;
    __syncthreads();
    if (!kh) {
      floatx4 Cp = *(const floatx4*)&red[(tile * 64 + lane) * 4];
#pragma unroll
      for (int r = 0; r < 4; ++r) {
        int m = quad * 4 + r;
        float xv = xl[m * 64 + n] + C[r] + Cp[r];
        xl[m * 64 + n] = xv;
        if (write_x) x[(size_t)(tok0 + m) * 64 + n] = xv;
      }
    }
  }
  __syncthreads();
}

__global__ __launch_bounds__(512, 4) void k_pf_qkv(
    const float* __restrict__ ob, const float* __restrict__ lsum,
    const unsigned short* __restrict__ arena,
    const float* __restrict__ bo, float* __restrict__ x,
    const float* __restrict__ ln2_s, const float* __restrict__ ln2_b,
    const float* __restrict__ b1, const float* __restrict__ b2, int lay,
    const float* __restrict__ ln1_s, const float* __restrict__ ln1_b,
    const float* __restrict__ bq, const float* __restrict__ bk,
    const float* __restrict__ bv, unsigned short* __restrict__ qo,
    unsigned short* __restrict__ ko, unsigned short* __restrict__ voT) {
  __shared__ __align__(16) unsigned short Ah[16 * 136], Al[16 * 136];
  __shared__ __align__(16) unsigned short Sh[16 * 72], Sl[16 * 72];
  __shared__ __align__(16) unsigned short Hh[16 * 264], Hl[16 * 264];
  __shared__ float xl[16 * 64];
  __shared__ __align__(16) float red[4 * 64 * 4];
  int t = threadIdx.x;
  int tok0 = blockIdx.x * 16;
  pf_body(ob, lsum, arena, bo, x, ln2_s, ln2_b, b1, b2, lay,
          Ah, Al, Sh, Sl, Hh, Hl, xl, red, tok0, t, true);
  qkv_tail(xl, Sh, Sl, arena, lay + 1, ln1_s, ln1_b, bq, bk, bv,
           qo, ko, voT, tok0, t);
}

__global__ __launch_bounds__(512, 4) void k_pf_head(
    const float* __restrict__ ob, const float* __restrict__ lsum,
    const unsigned short* __restrict__ arena,
    const float* __restrict__ bo, float* __restrict__ x,
    const float* __restrict__ ln2_s, const float* __restrict__ ln2_b,
    const float* __restrict__ b1, const float* __restrict__ b2, int lay,
    const float* __restrict__ bh1, const float* __restrict__ bh2,
    const float* __restrict__ Wh3, const float* __restrict__ bh3,
    float* __restrict__ out) {
  __shared__ __align__(16) unsigned short Ah[16 * 136], Al[16 * 136];
  __shared__ __align__(16) unsigned short Sh[16 * 72], Sl[16 * 72];
  __shared__ __align__(16) unsigned short Hh[16 * 264], Hl[16 * 264];
  __shared__ float xl[16 * 64];
  __shared__ __align__(16) float red[4 * 64 * 4];
  int t = threadIdx.x, w = t >> 6, lane = t & 63;
  int lq = lane & 15, quad = lane >> 4;
  int tok0 = blockIdx.x * 16;
  pf_body(ob, lsum, arena, bo, x, ln2_s, ln2_b, b1, b2, lay,
          Ah, Al, Sh, Sl, Hh, Hl, xl, red, tok0, t, false);
  // split raw x -> Sh/Sl (16 tokens over 8 waves)
#pragma unroll
  for (int tk = 0; tk < 2; ++tk) {
    int tok = w * 2 + tk;
    unsigned short hi, lo;
    split_bf(xl[tok * 64 + lane], hi, lo);
    Sh[tok * 72 + lane] = hi;
    Sl[tok * 72 + lane] = lo;
  }
  __syncthreads();
  // head G1: 64 -> 256, gelu. 16 col-tiles over 8 waves.
  {
    const unsigned short* Bh = arena + OFF_WH1;
    const unsigned short* Bl = Bh + 16384;
#pragma unroll
    for (int j = 0; j < 2; ++j) {
      int tl = w * 2 + j, n = tl * 16 + lq;
      float bb = bh1[n];
      floatx4 C = {bb, bb, bb, bb};
      C = mfma_tile<64, 72>(Sh, Sl, Bh + tl * 16 * 64, Bl + tl * 16 * 64,
                            lane, lq, quad, C);
#pragma unroll
      for (int r = 0; r < 4; ++r) {
        float g = gelu_tanh(C[r]);
        unsigned short hi, lo;
        split_bf(g, hi, lo);
        Hh[(quad * 4 + r) * 264 + n] = hi;
        Hl[(quad * 4 + r) * 264 + n] = lo;
      }
    }
  }
  __syncthreads();
  // head G2: 256 -> 64, gelu -> xl. K-split across wave pairs.
  {
    const unsigned short* Bh = arena + OFF_WH2;
    const unsigned short* Bl = Bh + 16384;
    int tile = w & 3, kh = w >> 2, koff = kh * 128;
    int n = tile * 16 + lq;
    floatx4 C = {0.0f, 0.0f, 0.0f, 0.0f};
    if (kh == 0) {
      float bb = bh2[n];
      C[0] = bb; C[1] = bb; C[2] = bb; C[3] = bb;
    }
    C = mfma_tile<128, 264>(Hh + koff, Hl + koff,
                            Bh + tile * 16 * 256 + (koff >> 5) * 512,
                            Bl + tile * 16 * 256 + (koff >> 5) * 512,
                            lane, lq, quad, C);
    if (kh) *(floatx4*)&red[(tile * 64 + lane) * 4] = C;
    __syncthreads();
    if (!kh) {
      floatx4 Cp = *(const floatx4*)&red[(tile * 64 + lane) * 4];
#pragma unroll
      for (int r = 0; r < 4; ++r)
        xl[(quad * 4 + r) * 64 + n] = gelu_tanh(C[r] + Cp[r]);
    }
  }
  __syncthreads();
  // head G3: dot with Wh3 (16 tokens over 8 waves)
  float wv3 = Wh3[lane];
#pragma unroll
  for (int tk = 0; tk < 2; ++tk) {
    int tok = w * 2 + tk;
    float v = xl[tok * 64 + lane] * wv3;
    float sum = wave_reduce_sum(v);
    if (lane == 0) out[tok0 + tok] = sum + bh3[0];
  }
}

extern "C" void kernel_launch(void* const* d_in, const int* in_sizes, int n_in,
                              void* d_out, int out_size, void* d_ws, size_t ws_size,
                              hipStream_t stream) {
  const float* z      = (const float*)d_in[0];
  const float* cond   = (const float*)d_in[1];
  const float* s      = (const float*)d_in[2];
  const float* embed  = (const float*)d_in[3];
  const float* Win1   = (const float*)d_in[4];
  const float* bin1   = (const float*)d_in[5];
  const float* Win2   = (const float*)d_in[6];
  const float* bin2   = (const float*)d_in[7];
  const float* ln1_s  = (const float*)d_in[8];
  const float* ln1_b  = (const float*)d_in[9];
  const float* ln2_s  = (const float*)d_in[10];
  const float* ln2_b  = (const float*)d_in[11];
  const float* Wq     = (const float*)d_in[12];
  const float* bq     = (const float*)d_in[13];
  const float* Wk     = (const float*)d_in[14];
  const float* bk     = (const float*)d_in[15];
  const float* Wv     = (const float*)d_in[16];
  const float* bv     = (const float*)d_in[17];
  const float* Wo     = (const float*)d_in[18];
  const float* bo     = (const float*)d_in[19];
  const float* rbf_c  = (const float*)d_in[20];
  const float* rbf_lw = (const float*)d_in[21];
  const float* rbf_w  = (const float*)d_in[22];
  const float* rbf_b  = (const float*)d_in[23];
  const float* W1     = (const float*)d_in[24];
  const float* b1     = (const float*)d_in[25];
  const float* W2     = (const float*)d_in[26];
  const float* b2     = (const float*)d_in[27];
  const float* Wh1    = (const float*)d_in[28];
  const float* bh1    = (const float*)d_in[29];
  const float* Wh2    = (const float*)d_in[30];
  const float* bh2    = (const float*)d_in[31];
  const float* Wh3    = (const float*)d_in[32];
  const float* bh3    = (const float*)d_in[33];

  char* base = (char*)d_ws;
  float*          x     = (float*)(base);                         // 2 MB
  unsigned short* qb    = (unsigned short*)(base + (2u << 20));   // 2 MB
  unsigned short* kb    = (unsigned short*)(base + (4u << 20));   // 2 MB
  unsigned short* vbT   = (unsigned short*)(base + (6u << 20));   // 2 MB
  float*          ob    = (float*)(base + (8u << 20));            // 4 x 4 MB
  float*          lsum  = (float*)(base + (24u << 20));           // 1 MB
  unsigned short* biasT = (unsigned short*)(base + (25u << 20));  // 2 x 16 MB
  unsigned short* arena = (unsigned short*)(base + (57u << 20));  // ~832 KB

  PrepArgs pa;
  auto set = [&](int i, const float* sp, int K, int N, int dst) {
    pa.src[i] = sp; pa.Kd[i] = K; pa.Nd[i] = N; pa.dst[i] = dst;
    pa.elems[i] = K * N;
  };
  set(0, Win1, 128, 256, OFF_WIN1);
  set(1, Win2, 256, 64, OFF_WIN2);
  for (int lay = 0; lay < 2; ++lay) {
    int lb = OFF_LAY0 + lay * LAY_STRIDE;
    set(2 + lay * 6, Wq + lay * 8192, 64, 128, lb + OFF_WQ);
    set(3 + lay * 6, Wk + lay * 8192, 64, 128, lb + OFF_WK);
    set(4 + lay * 6, Wv + lay * 8192, 64, 128, lb + OFF_WV);
    set(5 + lay * 6, Wo + lay * 8192, 128, 64, lb + OFF_WO);
    set(6 + lay * 6, W1 + lay * 16384, 64, 256, lb + OFF_W1);
    set(7 + lay * 6, W2 + lay * 16384, 256, 64, lb + OFF_W2);
  }
  set(14, Wh1, 64, 256, OFF_WH1);
  set(15, Wh2, 256, 64, OFF_WH2);

  k_prep_bias<<<2048 + 8192, 256, 0, stream>>>(pa, arena, s, rbf_c, rbf_lw,
                                               rbf_w, rbf_b, biasT);
  k_in_qkv<<<512, 512, 0, stream>>>(embed, z, cond, arena, bin1, bin2, x,
                                    ln1_s, ln1_b, bq, bk, bv, qb, kb, vbT);
  k_attn<<<4096, 256, 0, stream>>>(qb, kb, vbT, biasT, ob, lsum);
  k_pf_qkv<<<512, 512, 0, stream>>>(ob, lsum, arena, bo, x, ln2_s, ln2_b,
                                    b1, b2, 0, ln1_s, ln1_b, bq, bk, bv,
                                    qb, kb, vbT);
  k_attn<<<4096, 256, 0, stream>>>(qb, kb, vbT,
                                   biasT + (size_t)8 * 1024 * 1024, ob, lsum);
  k_pf_head<<<512, 512, 0, stream>>>(ob, lsum, arena, bo, x, ln2_s, ln2_b,
                                     b1, b2, 1, bh1, bh2, Wh3, bh3,
                                     (float*)d_out);
}